// Round 7
// baseline (408.622 us; speedup 1.0000x reference)
//
#include <hip/hip_runtime.h>

#define NNODES 65536
#define NDATA  32768
#define HID    128
#define HEADS  4
#define CHANS  32
#define LAYERS 4

using bf16x8 = __attribute__((ext_vector_type(8))) short;
using f32x4  = __attribute__((ext_vector_type(4))) float;

__device__ __forceinline__ float wave_reduce_sum(float v) {
#pragma unroll
    for (int m = 1; m < 64; m <<= 1) v += __shfl_xor(v, m, 64);
    return v;
}

__device__ __forceinline__ unsigned short bf16_rne(float f) {
    unsigned u = __float_as_uint(f);
    return (unsigned short)((u + 0x7fffu + ((u >> 16) & 1u)) >> 16);
}
__device__ __forceinline__ float bf2f(unsigned short u) {
    return __uint_as_float((unsigned)u << 16);
}

// ---------------- CSR build ----------------
__global__ void init_deg(int* __restrict__ deg) {
    int i = blockIdx.x * 256 + threadIdx.x;
    deg[i] = 1;  // self-loop
}

__global__ void hist_kernel(const int* __restrict__ ei, int* __restrict__ deg, int Eo) {
    int e = blockIdx.x * 256 + threadIdx.x;
    if (e >= Eo) return;
    atomicAdd(&deg[ei[Eo + e]], 1);   // dst row
}

__global__ void scan1(const int* __restrict__ deg, int* __restrict__ offs, int* __restrict__ bsum) {
    __shared__ int s[256];
    int t = threadIdx.x, b = blockIdx.x;
    int v = deg[b * 256 + t];
    s[t] = v;
    __syncthreads();
    for (int off = 1; off < 256; off <<= 1) {
        int add = (t >= off) ? s[t - off] : 0;
        __syncthreads();
        s[t] += add;
        __syncthreads();
    }
    offs[b * 256 + t] = s[t] - v;
    if (t == 255) bsum[b] = s[255];
}

__global__ void scan2(int* __restrict__ bsum) {
    __shared__ int s[256];
    int t = threadIdx.x;
    int v = bsum[t];
    s[t] = v;
    __syncthreads();
    for (int off = 1; off < 256; off <<= 1) {
        int add = (t >= off) ? s[t - off] : 0;
        __syncthreads();
        s[t] += add;
        __syncthreads();
    }
    bsum[t] = s[t] - v;
}

__global__ void scan3(int* __restrict__ offs, const int* __restrict__ bsum,
                      int* __restrict__ cursor, int Eo) {
    int i = blockIdx.x * 256 + threadIdx.x;
    int v = offs[i] + bsum[i >> 8];
    offs[i] = v;
    cursor[i] = v;
    if (i == 0) offs[NNODES] = Eo + NNODES;
}

__global__ void fill_kernel(const int* __restrict__ ei, int* __restrict__ cursor,
                            int* __restrict__ col, int Eo) {
    int e = blockIdx.x * 256 + threadIdx.x;
    int Etot = Eo + NNODES;
    if (e >= Etot) return;
    int src, dst;
    if (e < Eo) { src = ei[e]; dst = ei[Eo + e]; }
    else        { src = dst = e - Eo; }
    int pos = atomicAdd(&cursor[dst], 1);
    col[pos] = src;
}

// ------- weight prep: transpose + fused score cols + bf16 hi/lo split, FRAG-PACKED -------
__global__ void prep_wg(const float* __restrict__ Wg, const float* __restrict__ attS,
                        const float* __restrict__ attD,
                        unsigned short* __restrict__ wh, unsigned short* __restrict__ wl)
{
    int id = blockIdx.x * 256 + threadIdx.x;     // 4*144*128
    int l = id / (144 * 128);
    int rem = id % (144 * 128);
    int n = rem / 128, k = rem % 128;
    const float* W = Wg + (size_t)l * HID * HID;
    float v = 0.f;
    if (n < 128) {
        v = W[k * HID + n];
    } else if (n < 136) {
        int h = (n - 128) & 3;
        const float* av = ((n - 128) < 4 ? attS : attD) + l * HID + h * CHANS;
        for (int c = 0; c < CHANS; c++) v += W[k * HID + h * CHANS + c] * av[c];
    }
    unsigned short hh = bf16_rne(v);
    int t = n >> 4, bcol = n & 15;
    int ks = k >> 5, kq = (k >> 3) & 3, e = k & 7;
    size_t o = (size_t)l * (144 * 128) + (size_t)(((t * 4 + ks) * 64) + (kq * 16 + bcol)) * 8 + e;
    wh[o] = hh;
    wl[o] = bf16_rne(v - bf2f(hh));
}

// policy weights: transposed + split + frag-packed
__global__ void prep_pw(const float* __restrict__ pW1, const float* __restrict__ pW2,
                        unsigned short* __restrict__ w1h, unsigned short* __restrict__ w1l,
                        unsigned short* __restrict__ w2h, unsigned short* __restrict__ w2l)
{
    int id = blockIdx.x * 256 + threadIdx.x;     // 128*128 + 64*128 = 24576
    int n, k;
    float v;
    unsigned short *dh, *dl;
    if (id < 16384) {
        n = id / 128; k = id % 128;
        v = pW1[k * 128 + n];
        dh = w1h; dl = w1l;
    } else {
        int j = id - 16384;
        n = j / 128; k = j % 128;
        v = pW2[k * 64 + n];
        dh = w2h; dl = w2l;
    }
    unsigned short hh = bf16_rne(v);
    int t = n >> 4, bcol = n & 15;
    int ks = k >> 5, kq = (k >> 3) & 3, e = k & 7;
    size_t o = (size_t)(((t * 4 + ks) * 64) + (kq * 16 + bcol)) * 8 + e;
    dh[o] = hh;
    dl[o] = bf16_rne(v - bf2f(hh));
}

// value-net weights: transpose for row-contiguous per-thread reads
__global__ void prep_vw(const float* __restrict__ vW1, const float* __restrict__ vW2,
                        float* __restrict__ w1t, float* __restrict__ w2t)
{
    int id = blockIdx.x * 256 + threadIdx.x;     // 16384 + 8192 = 24576
    if (id < 16384) {
        int t = id >> 7, k = id & 127;
        w1t[t * 128 + k] = vW1[k * 128 + t];
    } else {
        int j = id - 16384;
        int t = j >> 7, k = j & 127;
        w2t[t * 128 + k] = vW2[k * 64 + t];
    }
}

// ---------------- embedding + LN + ReLU -> xh/xl split (warp per node) ----------------
__global__ __launch_bounds__(256) void embed_kernel(
    const float* __restrict__ feat, const float* __restrict__ W,
    const float* __restrict__ bb, const float* __restrict__ g,
    const float* __restrict__ be, unsigned short* __restrict__ xh,
    unsigned short* __restrict__ xl)
{
    int node = blockIdx.x * 4 + (threadIdx.x >> 6);
    int lane = threadIdx.x & 63;
    float f[10];
#pragma unroll
    for (int i = 0; i < 10; i++) f[i] = feat[node * 10 + i];
    int c0 = 2 * lane, c1 = c0 + 1;
    float v0 = bb[c0], v1 = bb[c1];
#pragma unroll
    for (int i = 0; i < 10; i++) {
        v0 = fmaf(f[i], W[i * HID + c0], v0);
        v1 = fmaf(f[i], W[i * HID + c1], v1);
    }
    float mu = wave_reduce_sum(v0 + v1) * (1.f / 128.f);
    float e0 = v0 - mu, e1 = v1 - mu;
    float var = wave_reduce_sum(e0 * e0 + e1 * e1) * (1.f / 128.f);
    float r = 1.f / sqrtf(var + 1e-5f);
    float r0 = fmaxf(e0 * r * g[c0] + be[c0], 0.f);
    float r1 = fmaxf(e1 * r * g[c1] + be[c1], 0.f);
    unsigned short h0 = bf16_rne(r0), h1 = bf16_rne(r1);
    unsigned short l0 = bf16_rne(r0 - bf2f(h0)), l1 = bf16_rne(r1 - bf2f(h1));
    size_t xi = (size_t)node * HID;
    *(unsigned*)(xh + xi + c0) = (unsigned)h0 | ((unsigned)h1 << 16);
    *(unsigned*)(xl + xi + c0) = (unsigned)l0 | ((unsigned)l1 << 16);
}

// ---------------- MFMA GEMM, K=128, bf16 hi/lo split (3-product fp32-equivalent) ----
// 256 thr = 4 waves; BM=64 rows; B staged in LDS in 2 K-phases.
// LDS 36.9KB max -> 4 blocks/CU; __launch_bounds__(256,4) caps VGPR<=128 -> 16 waves/CU.
// Inter-block phase stagger provides the memory/MFMA overlap (no explicit pipelining).
template <int NT, int EPI>
__global__ __launch_bounds__(256, 4) void mfma_gemm(
    const unsigned short* __restrict__ Ah, const unsigned short* __restrict__ Al,
    const unsigned short* __restrict__ Bh, const unsigned short* __restrict__ Bl,
    const float* __restrict__ bias,
    unsigned short* __restrict__ outH, unsigned short* __restrict__ outL,
    float* __restrict__ a_s, float* __restrict__ a_d, float* __restrict__ outF)
{
    // LDS layout per phase: frag_id = (t*2+ksl)*2 + lo ; elem off = frag_id*512 + lane*8
    __shared__ unsigned short lds[NT * 2048];

    int tid = threadIdx.x;
    int wid = tid >> 6, l = tid & 63;
    int row = blockIdx.x * 64 + wid * 16 + (l & 15);
    int kg = (l >> 4) * 8;

    const unsigned short* arh = Ah + (size_t)row * 128 + kg;
    const unsigned short* arl = Al + (size_t)row * 128 + kg;
    bf16x8 afh[4], afl[4];
#pragma unroll
    for (int ks = 0; ks < 4; ks++) {
        afh[ks] = *(const bf16x8*)(arh + ks * 32);
        afl[ks] = *(const bf16x8*)(arl + ks * 32);
    }

    f32x4 acc[NT];
#pragma unroll
    for (int t = 0; t < NT; t++) acc[t] = (f32x4){0.f, 0.f, 0.f, 0.f};

#pragma unroll
    for (int p = 0; p < 2; p++) {
        __syncthreads();   // ensure all waves done reading previous LDS contents
        // stage this phase's B frags (ks = 2p, 2p+1); uniform: 2*NT*128/256 iters/thread
        constexpr int HCH = NT * 128;
#pragma unroll
        for (int i = tid; i < 2 * HCH; i += 256) {
            int lo = (i >= HCH) ? 1 : 0;
            int j = lo ? (i - HCH) : i;
            int f = j >> 6;                    // t*2 + ksl
            int c = j & 63;
            int t = f >> 1, ksl = f & 1;
            const unsigned short* src = (lo ? Bl : Bh)
                + ((size_t)(t * 4 + p * 2 + ksl) << 9) + (c << 3);
            *(bf16x8*)&lds[(((f << 1) | lo) << 9) + (c << 3)] = *(const bf16x8*)src;
        }
        __syncthreads();
        // compute from LDS
#pragma unroll
        for (int ksl = 0; ksl < 2; ksl++) {
            int ks = p * 2 + ksl;
#pragma unroll
            for (int t = 0; t < NT; t++) {
                const unsigned short* bp = &lds[(((t * 2 + ksl) << 1) << 9) + (l << 3)];
                bf16x8 bh  = *(const bf16x8*)bp;
                bf16x8 blo = *(const bf16x8*)(bp + 512);
                acc[t] = __builtin_amdgcn_mfma_f32_16x16x32_bf16(afh[ks], bh,  acc[t], 0, 0, 0);
                acc[t] = __builtin_amdgcn_mfma_f32_16x16x32_bf16(afh[ks], blo, acc[t], 0, 0, 0);
                acc[t] = __builtin_amdgcn_mfma_f32_16x16x32_bf16(afl[ks], bh,  acc[t], 0, 0, 0);
            }
        }
    }

    // C/D layout: col = lane&15, row = (lane>>4)*4 + reg   [HW-verified]
    int ecol = l & 15;
    int er0 = blockIdx.x * 64 + wid * 16 + ((l >> 4) << 2);

    if constexpr (EPI == 0) {
#pragma unroll
        for (int t = 0; t < 8; t++)
#pragma unroll
            for (int j = 0; j < 4; j++)
                outH[(size_t)(er0 + j) * 128 + t * 16 + ecol] = bf16_rne(acc[t][j]);
#pragma unroll
        for (int j = 0; j < 4; j++) {
            float v = acc[8][j];
            if (ecol < 4)      a_s[(er0 + j) * 4 + ecol] = v;
            else if (ecol < 8) a_d[(er0 + j) * 4 + (ecol - 4)] = v;
        }
    } else if constexpr (EPI == 1) {
#pragma unroll
        for (int t = 0; t < NT; t++)
#pragma unroll
            for (int j = 0; j < 4; j++) {
                float v = fmaxf(acc[t][j] + bias[t * 16 + ecol], 0.f);
                unsigned short hh = bf16_rne(v);
                size_t o = (size_t)(er0 + j) * 128 + t * 16 + ecol;
                outH[o] = hh;
                outL[o] = bf16_rne(v - bf2f(hh));
            }
    } else {
#pragma unroll
        for (int t = 0; t < NT; t++)
#pragma unroll
            for (int j = 0; j < 4; j++) {
                float v = fmaxf(acc[t][j] + bias[t * 16 + ecol], 0.f);
                outF[(size_t)(er0 + j) * 64 + t * 16 + ecol] = v;
            }
    }
}

// ------- fused: per-dst softmax (no-max, denom-in-loop) + aggregate + bias/ReLU/res/LN ----
__global__ __launch_bounds__(256) void gat_agg(
    const unsigned short* __restrict__ hb, const float* __restrict__ a_s,
    const float* __restrict__ a_d, const int* __restrict__ offs,
    const int* __restrict__ col, const float* __restrict__ bgl,
    const float* __restrict__ gl, const float* __restrict__ bl,
    unsigned short* __restrict__ xh, unsigned short* __restrict__ xl)
{
    __shared__ float wsm[4][64][4];
    __shared__ int   ssm[4][64];
    int wv = threadIdx.x >> 6;
    int lane = threadIdx.x & 63;
    int node = blockIdx.x * 4 + wv;
    int s = offs[node], e = offs[node + 1];
    int deg = e - s;
    float4 ad = *(const float4*)(a_d + (size_t)node * 4);

    int c0 = 2 * lane, c1 = 2 * lane + 1;
    int head = lane >> 4;
    float acc0 = 0.f, acc1 = 0.f;
    float den = 1e-16f;

    if (deg <= 64) {
        if (lane < deg) {
            int src = col[s + lane];
            float4 as = *(const float4*)(a_s + (size_t)src * 4);
            float s0 = as.x + ad.x; s0 = (s0 > 0.f) ? s0 : 0.2f * s0;
            float s1 = as.y + ad.y; s1 = (s1 > 0.f) ? s1 : 0.2f * s1;
            float s2 = as.z + ad.z; s2 = (s2 > 0.f) ? s2 : 0.2f * s2;
            float s3 = as.w + ad.w; s3 = (s3 > 0.f) ? s3 : 0.2f * s3;
            *(float4*)&wsm[wv][lane][0] = make_float4(expf(s0), expf(s1), expf(s2), expf(s3));
            ssm[wv][lane] = src;
        }
        // same-wave LDS RAW: no barrier needed
        for (int j = 0; j < deg; j++) {
            int sj = ssm[wv][j];
            float wj = wsm[wv][j][head];
            den += wj;
            unsigned hv = *(const unsigned*)(hb + (((unsigned)sj << 7) + (unsigned)c0));
            acc0 = fmaf(wj, __uint_as_float(hv << 16), acc0);
            acc1 = fmaf(wj, __uint_as_float(hv & 0xffff0000u), acc1);
        }
    } else {
        for (int j = s; j < e; j++) {
            int src = col[j];
            float4 as = *(const float4*)(a_s + (size_t)src * 4);
            float sh = (head == 0) ? (as.x + ad.x) : (head == 1) ? (as.y + ad.y)
                     : (head == 2) ? (as.z + ad.z) : (as.w + ad.w);
            sh = (sh > 0.f) ? sh : 0.2f * sh;
            float wj = expf(sh);
            den += wj;
            unsigned hv = *(const unsigned*)(hb + (((unsigned)src << 7) + (unsigned)c0));
            acc0 = fmaf(wj, __uint_as_float(hv << 16), acc0);
            acc1 = fmaf(wj, __uint_as_float(hv & 0xffff0000u), acc1);
        }
    }
    float inv = 1.f / den;
    acc0 *= inv;
    acc1 *= inv;

    // epilogue: + bias, ReLU, residual (xh+xl), LayerNorm, write split x
    float o0 = fmaxf(acc0 + bgl[c0], 0.f);
    float o1 = fmaxf(acc1 + bgl[c1], 0.f);
    size_t xi = (size_t)node * HID;
    unsigned ph = *(const unsigned*)(xh + xi + c0);
    unsigned pl = *(const unsigned*)(xl + xi + c0);
    float x0 = __uint_as_float(ph << 16) + __uint_as_float(pl << 16);
    float x1 = __uint_as_float(ph & 0xffff0000u) + __uint_as_float(pl & 0xffff0000u);
    float t0 = x0 + o0, t1 = x1 + o1;
    float mu = wave_reduce_sum(t0 + t1) * (1.f / 128.f);
    float e0 = t0 - mu, e1 = t1 - mu;
    float var = wave_reduce_sum(e0 * e0 + e1 * e1) * (1.f / 128.f);
    float r = 1.f / sqrtf(var + 1e-5f);
    float r0 = e0 * r * gl[c0] + bl[c0];
    float r1 = e1 * r * gl[c1] + bl[c1];
    unsigned short h0 = bf16_rne(r0), h1 = bf16_rne(r1);
    unsigned short l0 = bf16_rne(r0 - bf2f(h0)), l1 = bf16_rne(r1 - bf2f(h1));
    *(unsigned*)(xh + xi + c0) = (unsigned)h0 | ((unsigned)h1 << 16);
    *(unsigned*)(xl + xi + c0) = (unsigned)l0 | ((unsigned)l1 << 16);
}

// ---------------- policy final layer: [NDATA,64] @ [64,2] ----------------
__global__ void policy3_kernel(const float* __restrict__ h2, const float* __restrict__ W,
                               const float* __restrict__ b, float* __restrict__ out)
{
    int rr = blockIdx.x * 256 + threadIdx.x;
    if (rr >= NDATA) return;
    const float* hr = h2 + (size_t)rr * 64;
    float o0 = b[0], o1 = b[1];
#pragma unroll
    for (int k = 0; k < 64; k++) {
        float v = hr[k];
        o0 = fmaf(v, W[k * 2 + 0], o0);
        o1 = fmaf(v, W[k * 2 + 1], o1);
    }
    out[rr * 2 + 0] = o0;
    out[rr * 2 + 1] = o1;
}

// ---------------- value head ----------------
__global__ void pool_zero(float* __restrict__ pool) { pool[threadIdx.x] = 0.f; }

__global__ void pool_sum(const unsigned short* __restrict__ xh,
                         const unsigned short* __restrict__ xl, float* __restrict__ pool) {
    int t = threadIdx.x;                 // 128 threads
    int base = blockIdx.x * 128;         // 128 nodes per block (512 blocks)
    float s = 0.f;
    for (int i = 0; i < 128; i++) {
        size_t idx = (size_t)(base + i) * HID + t;
        s += bf2f(xh[idx]) + bf2f(xl[idx]);
    }
    atomicAdd(&pool[t], s);
}

// transposed-weight value MLP: thread t reads its own contiguous weight row
__global__ void value_mlp(const float* __restrict__ pool,
                          const float* __restrict__ w1t, const float* __restrict__ b1,
                          const float* __restrict__ w2t, const float* __restrict__ b2,
                          const float* __restrict__ W3, const float* __restrict__ b3,
                          float* __restrict__ out)
{
    __shared__ float p[128], h1[128], h2[64];
    int t = threadIdx.x;   // 128
    p[t] = pool[t] * (1.f / (float)NNODES);
    __syncthreads();
    float a = b1[t];
    const float4* wr = (const float4*)(w1t + (size_t)t * 128);
#pragma unroll
    for (int k4 = 0; k4 < 32; k4++) {
        float4 w = wr[k4];
        a += p[4 * k4] * w.x + p[4 * k4 + 1] * w.y + p[4 * k4 + 2] * w.z + p[4 * k4 + 3] * w.w;
    }
    h1[t] = fmaxf(a, 0.f);
    __syncthreads();
    if (t < 64) {
        float a2 = b2[t];
        const float4* wr2 = (const float4*)(w2t + (size_t)t * 128);
#pragma unroll
        for (int k4 = 0; k4 < 32; k4++) {
            float4 w = wr2[k4];
            a2 += h1[4 * k4] * w.x + h1[4 * k4 + 1] * w.y + h1[4 * k4 + 2] * w.z + h1[4 * k4 + 3] * w.w;
        }
        h2[t] = fmaxf(a2, 0.f);
    }
    __syncthreads();
    if (t == 0) {
        float v = b3[0];
        for (int k = 0; k < 64; k++) v = fmaf(h2[k], W3[k], v);
        out[NDATA * 2] = v;
    }
}

extern "C" void kernel_launch(void* const* d_in, const int* in_sizes, int n_in,
                              void* d_out, int out_size, void* d_ws, size_t ws_size,
                              hipStream_t stream)
{
    const float* feat  = (const float*)d_in[0];
    const int*   ei    = (const int*)d_in[1];
    const float* W_emb = (const float*)d_in[2];
    const float* b_emb = (const float*)d_in[3];
    const float* ln0g  = (const float*)d_in[4];
    const float* ln0b  = (const float*)d_in[5];
    const float* Wg    = (const float*)d_in[6];
    const float* att_s = (const float*)d_in[7];
    const float* att_d = (const float*)d_in[8];
    const float* bg    = (const float*)d_in[9];
    const float* lng   = (const float*)d_in[10];
    const float* lnb   = (const float*)d_in[11];
    const float* pW1 = (const float*)d_in[12]; const float* pb1 = (const float*)d_in[13];
    const float* pW2 = (const float*)d_in[14]; const float* pb2 = (const float*)d_in[15];
    const float* pW3 = (const float*)d_in[16]; const float* pb3 = (const float*)d_in[17];
    const float* vW1 = (const float*)d_in[18]; const float* vb1 = (const float*)d_in[19];
    const float* vW2 = (const float*)d_in[20]; const float* vb2 = (const float*)d_in[21];
    const float* vW3 = (const float*)d_in[22]; const float* vb3 = (const float*)d_in[23];
    float* out = (float*)d_out;
    int Eo = in_sizes[1] / 2;

    // workspace layout
    unsigned short* xh = (unsigned short*)d_ws;              // 65536*128 bf16
    unsigned short* xl = xh + (size_t)NNODES * HID;
    unsigned short* hb = xl + (size_t)NNODES * HID;          // h bf16; reused as ph1h/ph1l
    float* a_s = (float*)(hb + (size_t)NNODES * HID);
    float* a_d = a_s + NNODES * HEADS;
    float* ph2 = a_d + NNODES * HEADS;                       // 32768*64 f32
    unsigned short* wgt_h = (unsigned short*)(ph2 + (size_t)NDATA * 64);  // 4*144*128
    unsigned short* wgt_l = wgt_h + 4 * 144 * 128;
    unsigned short* pw1h  = wgt_l + 4 * 144 * 128;           // 128*128
    unsigned short* pw1l  = pw1h + 128 * 128;
    unsigned short* pw2h  = pw1l + 128 * 128;                // 64*128
    unsigned short* pw2l  = pw2h + 64 * 128;
    float* w1t  = (float*)(pw2l + 64 * 128);                 // 128*128 f32
    float* w2t  = w1t + 128 * 128;                           // 64*128 f32
    int* deg    = (int*)(w2t + 64 * 128);
    int* offs   = deg + NNODES;
    int* cursor = offs + NNODES + 2;
    int* bsum   = cursor + NNODES;
    int* col    = bsum + 256;
    float* pool = (float*)(col + Eo + NNODES);
    unsigned short* ph1h = hb;
    unsigned short* ph1l = hb + (size_t)NDATA * HID;

    // weight prep
    prep_wg<<<4 * 144 * 128 / 256, 256, 0, stream>>>(Wg, att_s, att_d, wgt_h, wgt_l);
    prep_pw<<<(128 * 128 + 64 * 128) / 256, 256, 0, stream>>>(pW1, pW2, pw1h, pw1l, pw2h, pw2l);
    prep_vw<<<(128 * 128 + 64 * 128) / 256, 256, 0, stream>>>(vW1, vW2, w1t, w2t);

    // CSR build (dst -> src list), self-loops included
    init_deg<<<NNODES / 256, 256, 0, stream>>>(deg);
    hist_kernel<<<(Eo + 255) / 256, 256, 0, stream>>>(ei, deg, Eo);
    scan1<<<256, 256, 0, stream>>>(deg, offs, bsum);
    scan2<<<1, 256, 0, stream>>>(bsum);
    scan3<<<256, 256, 0, stream>>>(offs, bsum, cursor, Eo);
    fill_kernel<<<(Eo + NNODES + 255) / 256, 256, 0, stream>>>(ei, cursor, col, Eo);

    // embedding -> xh/xl
    embed_kernel<<<NNODES / 4, 256, 0, stream>>>(feat, W_emb, b_emb, ln0g, ln0b, xh, xl);

    // GAT layers
    for (int l = 0; l < LAYERS; l++) {
        mfma_gemm<9, 0><<<NNODES / 64, 256, 0, stream>>>(
            xh, xl, wgt_h + (size_t)l * 144 * 128, wgt_l + (size_t)l * 144 * 128,
            nullptr, hb, nullptr, a_s, a_d, nullptr);
        gat_agg<<<NNODES / 4, 256, 0, stream>>>(
            hb, a_s, a_d, offs, col, bg + l * HID, lng + l * HID, lnb + l * HID, xh, xl);
    }

    // policy head (rows 0..NDATA-1)
    mfma_gemm<8, 1><<<NDATA / 64, 256, 0, stream>>>(
        xh, xl, pw1h, pw1l, pb1, ph1h, ph1l, nullptr, nullptr, nullptr);
    mfma_gemm<4, 2><<<NDATA / 64, 256, 0, stream>>>(
        ph1h, ph1l, pw2h, pw2l, pb2, nullptr, nullptr, nullptr, nullptr, ph2);
    policy3_kernel<<<(NDATA + 255) / 256, 256, 0, stream>>>(ph2, pW3, pb3, out);

    // value head
    pool_zero<<<1, 128, 0, stream>>>(pool);
    pool_sum<<<512, 128, 0, stream>>>(xh, xl, pool);
    value_mlp<<<1, 128, 0, stream>>>(pool, w1t, vb1, w2t, vb2, vW3, vb3, out);
}

// Round 8
// 375.674 us; speedup vs baseline: 1.0877x; 1.0877x over previous
//
#include <hip/hip_runtime.h>

#define NNODES 65536
#define NDATA  32768
#define HID    128
#define HEADS  4
#define CHANS  32
#define LAYERS 4

using bf16x8 = __attribute__((ext_vector_type(8))) short;
using f32x4  = __attribute__((ext_vector_type(4))) float;

__device__ __forceinline__ float wave_reduce_sum(float v) {
#pragma unroll
    for (int m = 1; m < 64; m <<= 1) v += __shfl_xor(v, m, 64);
    return v;
}

__device__ __forceinline__ unsigned short bf16_rne(float f) {
    unsigned u = __float_as_uint(f);
    return (unsigned short)((u + 0x7fffu + ((u >> 16) & 1u)) >> 16);
}
__device__ __forceinline__ float bf2f(unsigned short u) {
    return __uint_as_float((unsigned)u << 16);
}

__device__ __forceinline__ void gload_lds16(const unsigned short* g, unsigned short* l) {
    __builtin_amdgcn_global_load_lds(
        (const __attribute__((address_space(1))) void*)g,
        (__attribute__((address_space(3))) void*)l, 16, 0, 0);
}

// ---------------- CSR build ----------------
__global__ void init_deg(int* __restrict__ deg) {
    int i = blockIdx.x * 256 + threadIdx.x;
    deg[i] = 1;  // self-loop
}

__global__ void hist_kernel(const int* __restrict__ ei, int* __restrict__ deg, int Eo) {
    int e = blockIdx.x * 256 + threadIdx.x;
    if (e >= Eo) return;
    atomicAdd(&deg[ei[Eo + e]], 1);   // dst row
}

__global__ void scan1(const int* __restrict__ deg, int* __restrict__ offs, int* __restrict__ bsum) {
    __shared__ int s[256];
    int t = threadIdx.x, b = blockIdx.x;
    int v = deg[b * 256 + t];
    s[t] = v;
    __syncthreads();
    for (int off = 1; off < 256; off <<= 1) {
        int add = (t >= off) ? s[t - off] : 0;
        __syncthreads();
        s[t] += add;
        __syncthreads();
    }
    offs[b * 256 + t] = s[t] - v;
    if (t == 255) bsum[b] = s[255];
}

__global__ void scan2(int* __restrict__ bsum) {
    __shared__ int s[256];
    int t = threadIdx.x;
    int v = bsum[t];
    s[t] = v;
    __syncthreads();
    for (int off = 1; off < 256; off <<= 1) {
        int add = (t >= off) ? s[t - off] : 0;
        __syncthreads();
        s[t] += add;
        __syncthreads();
    }
    bsum[t] = s[t] - v;
}

__global__ void scan3(int* __restrict__ offs, const int* __restrict__ bsum,
                      int* __restrict__ cursor, int Eo) {
    int i = blockIdx.x * 256 + threadIdx.x;
    int v = offs[i] + bsum[i >> 8];
    offs[i] = v;
    cursor[i] = v;
    if (i == 0) offs[NNODES] = Eo + NNODES;
}

__global__ void fill_kernel(const int* __restrict__ ei, int* __restrict__ cursor,
                            int* __restrict__ col, int Eo) {
    int e = blockIdx.x * 256 + threadIdx.x;
    int Etot = Eo + NNODES;
    if (e >= Etot) return;
    int src, dst;
    if (e < Eo) { src = ei[e]; dst = ei[Eo + e]; }
    else        { src = dst = e - Eo; }
    int pos = atomicAdd(&cursor[dst], 1);
    col[pos] = src;
}

// ------- weight prep: transpose + fused score cols + bf16 hi/lo split, FRAG-PACKED -------
__global__ void prep_wg(const float* __restrict__ Wg, const float* __restrict__ attS,
                        const float* __restrict__ attD,
                        unsigned short* __restrict__ wh, unsigned short* __restrict__ wl)
{
    int id = blockIdx.x * 256 + threadIdx.x;     // 4*144*128
    int l = id / (144 * 128);
    int rem = id % (144 * 128);
    int n = rem / 128, k = rem % 128;
    const float* W = Wg + (size_t)l * HID * HID;
    float v = 0.f;
    if (n < 128) {
        v = W[k * HID + n];
    } else if (n < 136) {
        int h = (n - 128) & 3;
        const float* av = ((n - 128) < 4 ? attS : attD) + l * HID + h * CHANS;
        for (int c = 0; c < CHANS; c++) v += W[k * HID + h * CHANS + c] * av[c];
    }
    unsigned short hh = bf16_rne(v);
    int t = n >> 4, bcol = n & 15;
    int ks = k >> 5, kq = (k >> 3) & 3, e = k & 7;
    size_t o = (size_t)l * (144 * 128) + (size_t)(((t * 4 + ks) * 64) + (kq * 16 + bcol)) * 8 + e;
    wh[o] = hh;
    wl[o] = bf16_rne(v - bf2f(hh));
}

// policy weights (split+frag-packed) AND value weights (transposed f32) in one kernel
__global__ void prep_heads(const float* __restrict__ pW1, const float* __restrict__ pW2,
                           const float* __restrict__ vW1, const float* __restrict__ vW2,
                           unsigned short* __restrict__ w1h, unsigned short* __restrict__ w1l,
                           unsigned short* __restrict__ w2h, unsigned short* __restrict__ w2l,
                           float* __restrict__ w1t, float* __restrict__ w2t)
{
    int id = blockIdx.x * 256 + threadIdx.x;     // 24576 + 24576
    if (id < 24576) {
        int n, k;
        float v;
        unsigned short *dh, *dl;
        if (id < 16384) {
            n = id / 128; k = id % 128;
            v = pW1[k * 128 + n];
            dh = w1h; dl = w1l;
        } else {
            int j = id - 16384;
            n = j / 128; k = j % 128;
            v = pW2[k * 64 + n];
            dh = w2h; dl = w2l;
        }
        unsigned short hh = bf16_rne(v);
        int t = n >> 4, bcol = n & 15;
        int ks = k >> 5, kq = (k >> 3) & 3, e = k & 7;
        size_t o = (size_t)(((t * 4 + ks) * 64) + (kq * 16 + bcol)) * 8 + e;
        dh[o] = hh;
        dl[o] = bf16_rne(v - bf2f(hh));
    } else {
        int j = id - 24576;
        if (j < 16384) {
            int t = j >> 7, k = j & 127;
            w1t[t * 128 + k] = vW1[k * 128 + t];
        } else {
            j -= 16384;
            int t = j >> 7, k = j & 127;
            w2t[t * 128 + k] = vW2[k * 64 + t];
        }
    }
}

// ---------------- embedding + LN + ReLU -> xh/xl split (warp per node) ----------------
__global__ __launch_bounds__(256) void embed_kernel(
    const float* __restrict__ feat, const float* __restrict__ W,
    const float* __restrict__ bb, const float* __restrict__ g,
    const float* __restrict__ be, unsigned short* __restrict__ xh,
    unsigned short* __restrict__ xl)
{
    int node = blockIdx.x * 4 + (threadIdx.x >> 6);
    int lane = threadIdx.x & 63;
    float f[10];
#pragma unroll
    for (int i = 0; i < 10; i++) f[i] = feat[node * 10 + i];
    int c0 = 2 * lane, c1 = c0 + 1;
    float v0 = bb[c0], v1 = bb[c1];
#pragma unroll
    for (int i = 0; i < 10; i++) {
        v0 = fmaf(f[i], W[i * HID + c0], v0);
        v1 = fmaf(f[i], W[i * HID + c1], v1);
    }
    float mu = wave_reduce_sum(v0 + v1) * (1.f / 128.f);
    float e0 = v0 - mu, e1 = v1 - mu;
    float var = wave_reduce_sum(e0 * e0 + e1 * e1) * (1.f / 128.f);
    float r = 1.f / sqrtf(var + 1e-5f);
    float r0 = fmaxf(e0 * r * g[c0] + be[c0], 0.f);
    float r1 = fmaxf(e1 * r * g[c1] + be[c1], 0.f);
    unsigned short h0 = bf16_rne(r0), h1 = bf16_rne(r1);
    unsigned short l0 = bf16_rne(r0 - bf2f(h0)), l1 = bf16_rne(r1 - bf2f(h1));
    size_t xi = (size_t)node * HID;
    *(unsigned*)(xh + xi + c0) = (unsigned)h0 | ((unsigned)h1 << 16);
    *(unsigned*)(xl + xi + c0) = (unsigned)l0 | ((unsigned)l1 << 16);
}

// ---------------- MFMA GEMM, K=128, bf16 hi/lo split (3-product fp32-equivalent) ----
// 512 thr = 8 waves; BM=128; B staged via global_load_lds (async, direct-to-LDS) in
// 2 K-phases. Frag-packed B: 1KB frag = 64 lanes x 16B, exactly the wave-uniform-base
// + lane*16 pattern global_load_lds requires.
// EPI 0: GAT (tiles 0..7 -> hb bf16; tile 8 cols 0..3 -> a_s, 4..7 -> a_d)
// EPI 1: bias+relu -> split bf16 outH/outL  (N=128)
// EPI 2: bias+relu + fused final layer [64]x[64,2] -> logits (shfl-reduce)
template <int NT, int EPI>
__global__ __launch_bounds__(512, 4) void mfma_gemm(
    const unsigned short* __restrict__ Ah, const unsigned short* __restrict__ Al,
    const unsigned short* __restrict__ Bh, const unsigned short* __restrict__ Bl,
    const float* __restrict__ bias,
    unsigned short* __restrict__ outH, unsigned short* __restrict__ outL,
    float* __restrict__ a_s, float* __restrict__ a_d,
    const float* __restrict__ wfin, const float* __restrict__ bfin,
    float* __restrict__ outF)
{
    __shared__ unsigned short lds[NT * 2048];

    int tid = threadIdx.x;
    int wid = tid >> 6, l = tid & 63;
    int row = blockIdx.x * 128 + wid * 16 + (l & 15);
    int kg = (l >> 4) * 8;

    const unsigned short* arh = Ah + (size_t)row * 128 + kg;
    const unsigned short* arl = Al + (size_t)row * 128 + kg;
    bf16x8 afh[4], afl[4];
#pragma unroll
    for (int ks = 0; ks < 4; ks++) {
        afh[ks] = *(const bf16x8*)(arh + ks * 32);
        afl[ks] = *(const bf16x8*)(arl + ks * 32);
    }

    f32x4 acc[NT];
#pragma unroll
    for (int t = 0; t < NT; t++) acc[t] = (f32x4){0.f, 0.f, 0.f, 0.f};

#pragma unroll
    for (int p = 0; p < 2; p++) {
        __syncthreads();   // all waves done reading previous LDS contents
        // async stage: chunk c (1KB) -> lds + c*1024; wave w issues chunks w, w+8, ...
        for (int c = wid; c < 4 * NT; c += 8) {
            int fr = c >> 1, lo = c & 1;
            int t = fr >> 1, ksl = fr & 1;
            const unsigned short* src = (lo ? Bl : Bh)
                + ((size_t)(t * 4 + p * 2 + ksl) << 9) + ((unsigned)l << 3);
            gload_lds16(src, &lds[(size_t)c << 9]);
        }
        __syncthreads();   // drains vmcnt (global_load_lds) before reads
        // compute from LDS
#pragma unroll
        for (int ksl = 0; ksl < 2; ksl++) {
            int ks = p * 2 + ksl;
#pragma unroll
            for (int t = 0; t < NT; t++) {
                const unsigned short* bp = &lds[(((t * 2 + ksl) << 1) << 9) + (l << 3)];
                bf16x8 bh  = *(const bf16x8*)bp;
                bf16x8 blo = *(const bf16x8*)(bp + 512);
                acc[t] = __builtin_amdgcn_mfma_f32_16x16x32_bf16(afh[ks], bh,  acc[t], 0, 0, 0);
                acc[t] = __builtin_amdgcn_mfma_f32_16x16x32_bf16(afh[ks], blo, acc[t], 0, 0, 0);
                acc[t] = __builtin_amdgcn_mfma_f32_16x16x32_bf16(afl[ks], bh,  acc[t], 0, 0, 0);
            }
        }
    }

    // C/D layout: col = lane&15, row = (lane>>4)*4 + reg   [HW-verified]
    int ecol = l & 15;
    int er0 = blockIdx.x * 128 + wid * 16 + ((l >> 4) << 2);

    if constexpr (EPI == 0) {
#pragma unroll
        for (int t = 0; t < 8; t++)
#pragma unroll
            for (int j = 0; j < 4; j++)
                outH[(size_t)(er0 + j) * 128 + t * 16 + ecol] = bf16_rne(acc[t][j]);
#pragma unroll
        for (int j = 0; j < 4; j++) {
            float v = acc[8][j];
            if (ecol < 4)      a_s[(er0 + j) * 4 + ecol] = v;
            else if (ecol < 8) a_d[(er0 + j) * 4 + (ecol - 4)] = v;
        }
    } else if constexpr (EPI == 1) {
#pragma unroll
        for (int t = 0; t < NT; t++)
#pragma unroll
            for (int j = 0; j < 4; j++) {
                float v = fmaxf(acc[t][j] + bias[t * 16 + ecol], 0.f);
                unsigned short hh = bf16_rne(v);
                size_t o = (size_t)(er0 + j) * 128 + t * 16 + ecol;
                outH[o] = hh;
                outL[o] = bf16_rne(v - bf2f(hh));
            }
    } else {
        // bias+relu then fused [64]x[64,2]: partial per lane, reduce over 16-lane col group
        float p0[4], p1[4];
#pragma unroll
        for (int j = 0; j < 4; j++) { p0[j] = 0.f; p1[j] = 0.f; }
#pragma unroll
        for (int t = 0; t < NT; t++) {
            int cc = t * 16 + ecol;
            float w0 = wfin[cc * 2 + 0], w1 = wfin[cc * 2 + 1];
#pragma unroll
            for (int j = 0; j < 4; j++) {
                float v = fmaxf(acc[t][j] + bias[cc], 0.f);
                p0[j] = fmaf(v, w0, p0[j]);
                p1[j] = fmaf(v, w1, p1[j]);
            }
        }
#pragma unroll
        for (int m = 1; m < 16; m <<= 1)
#pragma unroll
            for (int j = 0; j < 4; j++) {
                p0[j] += __shfl_xor(p0[j], m, 64);
                p1[j] += __shfl_xor(p1[j], m, 64);
            }
        if (ecol == 0) {
            float b0 = bfin[0], b1 = bfin[1];
#pragma unroll
            for (int j = 0; j < 4; j++) {
                outF[(er0 + j) * 2 + 0] = p0[j] + b0;
                outF[(er0 + j) * 2 + 1] = p1[j] + b1;
            }
        }
    }
}

// ------- fused: per-dst softmax (no-max, denom-in-loop) + aggregate + bias/ReLU/res/LN ----
__global__ __launch_bounds__(256) void gat_agg(
    const unsigned short* __restrict__ hb, const float* __restrict__ a_s,
    const float* __restrict__ a_d, const int* __restrict__ offs,
    const int* __restrict__ col, const float* __restrict__ bgl,
    const float* __restrict__ gl, const float* __restrict__ bl,
    unsigned short* __restrict__ xh, unsigned short* __restrict__ xl)
{
    __shared__ float wsm[4][64][4];
    __shared__ int   ssm[4][64];
    int wv = threadIdx.x >> 6;
    int lane = threadIdx.x & 63;
    int node = blockIdx.x * 4 + wv;
    int s = offs[node], e = offs[node + 1];
    int deg = e - s;
    float4 ad = *(const float4*)(a_d + (size_t)node * 4);

    int c0 = 2 * lane, c1 = 2 * lane + 1;
    int head = lane >> 4;
    float acc0 = 0.f, acc1 = 0.f;
    float den = 1e-16f;

    if (deg <= 64) {
        if (lane < deg) {
            int src = col[s + lane];
            float4 as = *(const float4*)(a_s + (size_t)src * 4);
            float s0 = as.x + ad.x; s0 = (s0 > 0.f) ? s0 : 0.2f * s0;
            float s1 = as.y + ad.y; s1 = (s1 > 0.f) ? s1 : 0.2f * s1;
            float s2 = as.z + ad.z; s2 = (s2 > 0.f) ? s2 : 0.2f * s2;
            float s3 = as.w + ad.w; s3 = (s3 > 0.f) ? s3 : 0.2f * s3;
            *(float4*)&wsm[wv][lane][0] = make_float4(expf(s0), expf(s1), expf(s2), expf(s3));
            ssm[wv][lane] = src;
        }
        // same-wave LDS RAW: no barrier needed
        for (int j = 0; j < deg; j++) {
            int sj = ssm[wv][j];
            float wj = wsm[wv][j][head];
            den += wj;
            unsigned hv = *(const unsigned*)(hb + (((unsigned)sj << 7) + (unsigned)c0));
            acc0 = fmaf(wj, __uint_as_float(hv << 16), acc0);
            acc1 = fmaf(wj, __uint_as_float(hv & 0xffff0000u), acc1);
        }
    } else {
        for (int j = s; j < e; j++) {
            int src = col[j];
            float4 as = *(const float4*)(a_s + (size_t)src * 4);
            float sh = (head == 0) ? (as.x + ad.x) : (head == 1) ? (as.y + ad.y)
                     : (head == 2) ? (as.z + ad.z) : (as.w + ad.w);
            sh = (sh > 0.f) ? sh : 0.2f * sh;
            float wj = expf(sh);
            den += wj;
            unsigned hv = *(const unsigned*)(hb + (((unsigned)src << 7) + (unsigned)c0));
            acc0 = fmaf(wj, __uint_as_float(hv << 16), acc0);
            acc1 = fmaf(wj, __uint_as_float(hv & 0xffff0000u), acc1);
        }
    }
    float inv = 1.f / den;
    acc0 *= inv;
    acc1 *= inv;

    // epilogue: + bias, ReLU, residual (xh+xl), LayerNorm, write split x
    float o0 = fmaxf(acc0 + bgl[c0], 0.f);
    float o1 = fmaxf(acc1 + bgl[c1], 0.f);
    size_t xi = (size_t)node * HID;
    unsigned ph = *(const unsigned*)(xh + xi + c0);
    unsigned pl = *(const unsigned*)(xl + xi + c0);
    float x0 = __uint_as_float(ph << 16) + __uint_as_float(pl << 16);
    float x1 = __uint_as_float(ph & 0xffff0000u) + __uint_as_float(pl & 0xffff0000u);
    float t0 = x0 + o0, t1 = x1 + o1;
    float mu = wave_reduce_sum(t0 + t1) * (1.f / 128.f);
    float e0 = t0 - mu, e1 = t1 - mu;
    float var = wave_reduce_sum(e0 * e0 + e1 * e1) * (1.f / 128.f);
    float r = 1.f / sqrtf(var + 1e-5f);
    float r0 = e0 * r * gl[c0] + bl[c0];
    float r1 = e1 * r * gl[c1] + bl[c1];
    unsigned short h0 = bf16_rne(r0), h1 = bf16_rne(r1);
    unsigned short l0 = bf16_rne(r0 - bf2f(h0)), l1 = bf16_rne(r1 - bf2f(h1));
    *(unsigned*)(xh + xi + c0) = (unsigned)h0 | ((unsigned)h1 << 16);
    *(unsigned*)(xl + xi + c0) = (unsigned)l0 | ((unsigned)l1 << 16);
}

// ---------------- value head ----------------
// partial sums: 256 blocks x 128 threads, each block sums 256 nodes (no atomics)
__global__ void pool_sum(const unsigned short* __restrict__ xh,
                         const unsigned short* __restrict__ xl, float* __restrict__ partial) {
    int t = threadIdx.x;
    int base = blockIdx.x * 256;
    float s = 0.f;
    for (int i = 0; i < 256; i++) {
        size_t idx = (size_t)(base + i) * HID + t;
        s += bf2f(xh[idx]) + bf2f(xl[idx]);
    }
    partial[blockIdx.x * 128 + t] = s;
}

// transposed-weight value MLP; reduces 256 partials first
__global__ void value_mlp(const float* __restrict__ partial,
                          const float* __restrict__ w1t, const float* __restrict__ b1,
                          const float* __restrict__ w2t, const float* __restrict__ b2,
                          const float* __restrict__ W3, const float* __restrict__ b3,
                          float* __restrict__ out)
{
    __shared__ float p[128], h1[128], h2[64];
    int t = threadIdx.x;   // 128
    float s = 0.f;
    for (int i = 0; i < 256; i++) s += partial[i * 128 + t];
    p[t] = s * (1.f / (float)NNODES);
    __syncthreads();
    float a = b1[t];
    const float4* wr = (const float4*)(w1t + (size_t)t * 128);
#pragma unroll
    for (int k4 = 0; k4 < 32; k4++) {
        float4 w = wr[k4];
        a += p[4 * k4] * w.x + p[4 * k4 + 1] * w.y + p[4 * k4 + 2] * w.z + p[4 * k4 + 3] * w.w;
    }
    h1[t] = fmaxf(a, 0.f);
    __syncthreads();
    if (t < 64) {
        float a2 = b2[t];
        const float4* wr2 = (const float4*)(w2t + (size_t)t * 128);
#pragma unroll
        for (int k4 = 0; k4 < 32; k4++) {
            float4 w = wr2[k4];
            a2 += h1[4 * k4] * w.x + h1[4 * k4 + 1] * w.y + h1[4 * k4 + 2] * w.z + h1[4 * k4 + 3] * w.w;
        }
        h2[t] = fmaxf(a2, 0.f);
    }
    __syncthreads();
    if (t == 0) {
        float v = b3[0];
        for (int k = 0; k < 64; k++) v = fmaf(h2[k], W3[k], v);
        out[NDATA * 2] = v;
    }
}

extern "C" void kernel_launch(void* const* d_in, const int* in_sizes, int n_in,
                              void* d_out, int out_size, void* d_ws, size_t ws_size,
                              hipStream_t stream)
{
    const float* feat  = (const float*)d_in[0];
    const int*   ei    = (const int*)d_in[1];
    const float* W_emb = (const float*)d_in[2];
    const float* b_emb = (const float*)d_in[3];
    const float* ln0g  = (const float*)d_in[4];
    const float* ln0b  = (const float*)d_in[5];
    const float* Wg    = (const float*)d_in[6];
    const float* att_s = (const float*)d_in[7];
    const float* att_d = (const float*)d_in[8];
    const float* bg    = (const float*)d_in[9];
    const float* lng   = (const float*)d_in[10];
    const float* lnb   = (const float*)d_in[11];
    const float* pW1 = (const float*)d_in[12]; const float* pb1 = (const float*)d_in[13];
    const float* pW2 = (const float*)d_in[14]; const float* pb2 = (const float*)d_in[15];
    const float* pW3 = (const float*)d_in[16]; const float* pb3 = (const float*)d_in[17];
    const float* vW1 = (const float*)d_in[18]; const float* vb1 = (const float*)d_in[19];
    const float* vW2 = (const float*)d_in[20]; const float* vb2 = (const float*)d_in[21];
    const float* vW3 = (const float*)d_in[22]; const float* vb3 = (const float*)d_in[23];
    float* out = (float*)d_out;
    int Eo = in_sizes[1] / 2;

    // workspace layout
    unsigned short* xh = (unsigned short*)d_ws;              // 65536*128 bf16
    unsigned short* xl = xh + (size_t)NNODES * HID;
    unsigned short* hb = xl + (size_t)NNODES * HID;          // h bf16; reused as ph1h/ph1l
    float* a_s = (float*)(hb + (size_t)NNODES * HID);
    float* a_d = a_s + NNODES * HEADS;
    unsigned short* wgt_h = (unsigned short*)(a_d + NNODES * HEADS);  // 4*144*128
    unsigned short* wgt_l = wgt_h + 4 * 144 * 128;
    unsigned short* pw1h  = wgt_l + 4 * 144 * 128;           // 128*128
    unsigned short* pw1l  = pw1h + 128 * 128;
    unsigned short* pw2h  = pw1l + 128 * 128;                // 64*128
    unsigned short* pw2l  = pw2h + 64 * 128;
    float* w1t  = (float*)(pw2l + 64 * 128);                 // 128*128 f32
    float* w2t  = w1t + 128 * 128;                           // 64*128 f32
    float* partial = w2t + 64 * 128;                         // 256*128 f32
    int* deg    = (int*)(partial + 256 * 128);
    int* offs   = deg + NNODES;
    int* cursor = offs + NNODES + 2;
    int* bsum   = cursor + NNODES;
    int* col    = bsum + 256;
    unsigned short* ph1h = hb;
    unsigned short* ph1l = hb + (size_t)NDATA * HID;

    // weight prep
    prep_wg<<<4 * 144 * 128 / 256, 256, 0, stream>>>(Wg, att_s, att_d, wgt_h, wgt_l);
    prep_heads<<<192, 256, 0, stream>>>(pW1, pW2, vW1, vW2,
                                        pw1h, pw1l, pw2h, pw2l, w1t, w2t);

    // CSR build (dst -> src list), self-loops included
    init_deg<<<NNODES / 256, 256, 0, stream>>>(deg);
    hist_kernel<<<(Eo + 255) / 256, 256, 0, stream>>>(ei, deg, Eo);
    scan1<<<256, 256, 0, stream>>>(deg, offs, bsum);
    scan2<<<1, 256, 0, stream>>>(bsum);
    scan3<<<256, 256, 0, stream>>>(offs, bsum, cursor, Eo);
    fill_kernel<<<(Eo + NNODES + 255) / 256, 256, 0, stream>>>(ei, cursor, col, Eo);

    // embedding -> xh/xl
    embed_kernel<<<NNODES / 4, 256, 0, stream>>>(feat, W_emb, b_emb, ln0g, ln0b, xh, xl);

    // GAT layers
    for (int l = 0; l < LAYERS; l++) {
        mfma_gemm<9, 0><<<NNODES / 128, 512, 0, stream>>>(
            xh, xl, wgt_h + (size_t)l * 144 * 128, wgt_l + (size_t)l * 144 * 128,
            nullptr, hb, nullptr, a_s, a_d, nullptr, nullptr, nullptr);
        gat_agg<<<NNODES / 4, 256, 0, stream>>>(
            hb, a_s, a_d, offs, col, bg + l * HID, lng + l * HID, lnb + l * HID, xh, xl);
    }

    // policy head (rows 0..NDATA-1); final [64,2] layer fused into 2nd GEMM epilogue
    mfma_gemm<8, 1><<<NDATA / 128, 512, 0, stream>>>(
        xh, xl, pw1h, pw1l, pb1, ph1h, ph1l, nullptr, nullptr, nullptr, nullptr, nullptr);
    mfma_gemm<4, 2><<<NDATA / 128, 512, 0, stream>>>(
        ph1h, ph1l, pw2h, pw2l, pb2, nullptr, nullptr, nullptr, nullptr, pW3, pb3, out);

    // value head
    pool_sum<<<256, 128, 0, stream>>>(xh, xl, partial);
    value_mlp<<<1, 128, 0, stream>>>(partial, w1t, vb1, w2t, vb2, vW3, vb3, out);
}

// Round 9
// 359.255 us; speedup vs baseline: 1.1374x; 1.0457x over previous
//
#include <hip/hip_runtime.h>

#define NNODES 65536
#define NDATA  32768
#define HID    128
#define HEADS  4
#define CHANS  32
#define LAYERS 4

using bf16x8 = __attribute__((ext_vector_type(8))) short;
using f32x4  = __attribute__((ext_vector_type(4))) float;

__device__ __forceinline__ float wave_reduce_sum(float v) {
#pragma unroll
    for (int m = 1; m < 64; m <<= 1) v += __shfl_xor(v, m, 64);
    return v;
}

__device__ __forceinline__ unsigned short bf16_rne(float f) {
    unsigned u = __float_as_uint(f);
    return (unsigned short)((u + 0x7fffu + ((u >> 16) & 1u)) >> 16);
}
__device__ __forceinline__ float bf2f(unsigned short u) {
    return __uint_as_float((unsigned)u << 16);
}

__device__ __forceinline__ void gload_lds16(const unsigned short* g, unsigned short* l) {
    __builtin_amdgcn_global_load_lds(
        (const __attribute__((address_space(1))) void*)g,
        (__attribute__((address_space(3))) void*)l, 16, 0, 0);
}

// ---------------- CSR build ----------------
__global__ void hist_kernel(const int* __restrict__ ei, int* __restrict__ deg, int Eo) {
    int e = blockIdx.x * 256 + threadIdx.x;
    if (e >= Eo) return;
    atomicAdd(&deg[ei[Eo + e]], 1);   // dst row
}

// reads deg+1 (self-loop folded here; deg zeroed by memset)
__global__ void scan1(const int* __restrict__ deg, int* __restrict__ offs, int* __restrict__ bsum) {
    __shared__ int s[256];
    int t = threadIdx.x, b = blockIdx.x;
    int v = deg[b * 256 + t] + 1;
    s[t] = v;
    __syncthreads();
    for (int off = 1; off < 256; off <<= 1) {
        int add = (t >= off) ? s[t - off] : 0;
        __syncthreads();
        s[t] += add;
        __syncthreads();
    }
    offs[b * 256 + t] = s[t] - v;
    if (t == 255) bsum[b] = s[255];
}

__global__ void scan2(int* __restrict__ bsum) {
    __shared__ int s[256];
    int t = threadIdx.x;
    int v = bsum[t];
    s[t] = v;
    __syncthreads();
    for (int off = 1; off < 256; off <<= 1) {
        int add = (t >= off) ? s[t - off] : 0;
        __syncthreads();
        s[t] += add;
        __syncthreads();
    }
    bsum[t] = s[t] - v;
}

__global__ void scan3(int* __restrict__ offs, const int* __restrict__ bsum,
                      int* __restrict__ cursor, int Eo) {
    int i = blockIdx.x * 256 + threadIdx.x;
    int v = offs[i] + bsum[i >> 8];
    offs[i] = v;
    cursor[i] = v;
    if (i == 0) offs[NNODES] = Eo + NNODES;
}

__global__ void fill_kernel(const int* __restrict__ ei, int* __restrict__ cursor,
                            int* __restrict__ col, int Eo) {
    int e = blockIdx.x * 256 + threadIdx.x;
    int Etot = Eo + NNODES;
    if (e >= Etot) return;
    int src, dst;
    if (e < Eo) { src = ei[e]; dst = ei[Eo + e]; }
    else        { src = dst = e - Eo; }
    int pos = atomicAdd(&cursor[dst], 1);
    col[pos] = src;
}

// ------- weight prep: transpose + fused score cols + bf16 hi/lo split, FRAG-PACKED -------
__global__ void prep_wg(const float* __restrict__ Wg, const float* __restrict__ attS,
                        const float* __restrict__ attD,
                        unsigned short* __restrict__ wh, unsigned short* __restrict__ wl)
{
    int id = blockIdx.x * 256 + threadIdx.x;     // 4*144*128
    int l = id / (144 * 128);
    int rem = id % (144 * 128);
    int n = rem / 128, k = rem % 128;
    const float* W = Wg + (size_t)l * HID * HID;
    float v = 0.f;
    if (n < 128) {
        v = W[k * HID + n];
    } else if (n < 136) {
        int h = (n - 128) & 3;
        const float* av = ((n - 128) < 4 ? attS : attD) + l * HID + h * CHANS;
        for (int c = 0; c < CHANS; c++) v += W[k * HID + h * CHANS + c] * av[c];
    }
    unsigned short hh = bf16_rne(v);
    int t = n >> 4, bcol = n & 15;
    int ks = k >> 5, kq = (k >> 3) & 3, e = k & 7;
    size_t o = (size_t)l * (144 * 128) + (size_t)(((t * 4 + ks) * 64) + (kq * 16 + bcol)) * 8 + e;
    wh[o] = hh;
    wl[o] = bf16_rne(v - bf2f(hh));
}

// policy weights (split+frag-packed) AND value weights (transposed f32) in one kernel
__global__ void prep_heads(const float* __restrict__ pW1, const float* __restrict__ pW2,
                           const float* __restrict__ vW1, const float* __restrict__ vW2,
                           unsigned short* __restrict__ w1h, unsigned short* __restrict__ w1l,
                           unsigned short* __restrict__ w2h, unsigned short* __restrict__ w2l,
                           float* __restrict__ w1t, float* __restrict__ w2t)
{
    int id = blockIdx.x * 256 + threadIdx.x;     // 24576 + 24576
    if (id < 24576) {
        int n, k;
        float v;
        unsigned short *dh, *dl;
        if (id < 16384) {
            n = id / 128; k = id % 128;
            v = pW1[k * 128 + n];
            dh = w1h; dl = w1l;
        } else {
            int j = id - 16384;
            n = j / 128; k = j % 128;
            v = pW2[k * 64 + n];
            dh = w2h; dl = w2l;
        }
        unsigned short hh = bf16_rne(v);
        int t = n >> 4, bcol = n & 15;
        int ks = k >> 5, kq = (k >> 3) & 3, e = k & 7;
        size_t o = (size_t)(((t * 4 + ks) * 64) + (kq * 16 + bcol)) * 8 + e;
        dh[o] = hh;
        dl[o] = bf16_rne(v - bf2f(hh));
    } else {
        int j = id - 24576;
        if (j < 16384) {
            int t = j >> 7, k = j & 127;
            w1t[t * 128 + k] = vW1[k * 128 + t];
        } else {
            j -= 16384;
            int t = j >> 7, k = j & 127;
            w2t[t * 128 + k] = vW2[k * 64 + t];
        }
    }
}

// ---------------- embedding + LN + ReLU -> xh/xl split (warp per node) ----------------
__global__ __launch_bounds__(256) void embed_kernel(
    const float* __restrict__ feat, const float* __restrict__ W,
    const float* __restrict__ bb, const float* __restrict__ g,
    const float* __restrict__ be, unsigned short* __restrict__ xh,
    unsigned short* __restrict__ xl)
{
    int node = blockIdx.x * 4 + (threadIdx.x >> 6);
    int lane = threadIdx.x & 63;
    float f[10];
#pragma unroll
    for (int i = 0; i < 10; i++) f[i] = feat[node * 10 + i];
    int c0 = 2 * lane, c1 = c0 + 1;
    float v0 = bb[c0], v1 = bb[c1];
#pragma unroll
    for (int i = 0; i < 10; i++) {
        v0 = fmaf(f[i], W[i * HID + c0], v0);
        v1 = fmaf(f[i], W[i * HID + c1], v1);
    }
    float mu = wave_reduce_sum(v0 + v1) * (1.f / 128.f);
    float e0 = v0 - mu, e1 = v1 - mu;
    float var = wave_reduce_sum(e0 * e0 + e1 * e1) * (1.f / 128.f);
    float r = 1.f / sqrtf(var + 1e-5f);
    float r0 = fmaxf(e0 * r * g[c0] + be[c0], 0.f);
    float r1 = fmaxf(e1 * r * g[c1] + be[c1], 0.f);
    unsigned short h0 = bf16_rne(r0), h1 = bf16_rne(r1);
    unsigned short l0 = bf16_rne(r0 - bf2f(h0)), l1 = bf16_rne(r1 - bf2f(h1));
    size_t xi = (size_t)node * HID;
    *(unsigned*)(xh + xi + c0) = (unsigned)h0 | ((unsigned)h1 << 16);
    *(unsigned*)(xl + xi + c0) = (unsigned)l0 | ((unsigned)l1 << 16);
}

// ---------------- MFMA GEMM, K=128, bf16 hi/lo split ----
// 512 thr = 8 waves; BM=128; B staged via global_load_lds in 2 K-phases.
// ALO: include A-lo product (3-product fp32-equiv); false = 2-product (A bf16-hi only).
// EPI 0: GAT (tiles 0..7 -> hb bf16; tile 8 cols 0..3 -> a_s, 4..7 -> a_d)
// EPI 1: bias+relu -> bf16 outH (hi only)
// EPI 2: bias+relu + fused final layer [64]x[64,2] -> logits (shfl-reduce)
template <int NT, int EPI, bool ALO>
__global__ __launch_bounds__(512, 4) void mfma_gemm(
    const unsigned short* __restrict__ Ah, const unsigned short* __restrict__ Al,
    const unsigned short* __restrict__ Bh, const unsigned short* __restrict__ Bl,
    const float* __restrict__ bias,
    unsigned short* __restrict__ outH,
    float* __restrict__ a_s, float* __restrict__ a_d,
    const float* __restrict__ wfin, const float* __restrict__ bfin,
    float* __restrict__ outF)
{
    __shared__ unsigned short lds[NT * 2048];

    int tid = threadIdx.x;
    int wid = tid >> 6, l = tid & 63;
    int row = blockIdx.x * 128 + wid * 16 + (l & 15);
    int kg = (l >> 4) * 8;

    const unsigned short* arh = Ah + (size_t)row * 128 + kg;
    bf16x8 afh[4], afl[4];
#pragma unroll
    for (int ks = 0; ks < 4; ks++) afh[ks] = *(const bf16x8*)(arh + ks * 32);
    if constexpr (ALO) {
        const unsigned short* arl = Al + (size_t)row * 128 + kg;
#pragma unroll
        for (int ks = 0; ks < 4; ks++) afl[ks] = *(const bf16x8*)(arl + ks * 32);
    }

    f32x4 acc[NT];
#pragma unroll
    for (int t = 0; t < NT; t++) acc[t] = (f32x4){0.f, 0.f, 0.f, 0.f};

#pragma unroll
    for (int p = 0; p < 2; p++) {
        __syncthreads();   // all waves done reading previous LDS contents
        for (int c = wid; c < 4 * NT; c += 8) {
            int fr = c >> 1, lo = c & 1;
            int t = fr >> 1, ksl = fr & 1;
            const unsigned short* src = (lo ? Bl : Bh)
                + ((size_t)(t * 4 + p * 2 + ksl) << 9) + ((unsigned)l << 3);
            gload_lds16(src, &lds[(size_t)c << 9]);
        }
        __syncthreads();   // drains vmcnt (global_load_lds) before reads
#pragma unroll
        for (int ksl = 0; ksl < 2; ksl++) {
            int ks = p * 2 + ksl;
#pragma unroll
            for (int t = 0; t < NT; t++) {
                const unsigned short* bp = &lds[(((t * 2 + ksl) << 1) << 9) + (l << 3)];
                bf16x8 bh  = *(const bf16x8*)bp;
                bf16x8 blo = *(const bf16x8*)(bp + 512);
                acc[t] = __builtin_amdgcn_mfma_f32_16x16x32_bf16(afh[ks], bh,  acc[t], 0, 0, 0);
                acc[t] = __builtin_amdgcn_mfma_f32_16x16x32_bf16(afh[ks], blo, acc[t], 0, 0, 0);
                if constexpr (ALO)
                    acc[t] = __builtin_amdgcn_mfma_f32_16x16x32_bf16(afl[ks], bh, acc[t], 0, 0, 0);
            }
        }
    }

    // C/D layout: col = lane&15, row = (lane>>4)*4 + reg   [HW-verified]
    int ecol = l & 15;
    int er0 = blockIdx.x * 128 + wid * 16 + ((l >> 4) << 2);

    if constexpr (EPI == 0) {
#pragma unroll
        for (int t = 0; t < 8; t++)
#pragma unroll
            for (int j = 0; j < 4; j++)
                outH[(size_t)(er0 + j) * 128 + t * 16 + ecol] = bf16_rne(acc[t][j]);
#pragma unroll
        for (int j = 0; j < 4; j++) {
            float v = acc[8][j];
            if (ecol < 4)      a_s[(er0 + j) * 4 + ecol] = v;
            else if (ecol < 8) a_d[(er0 + j) * 4 + (ecol - 4)] = v;
        }
    } else if constexpr (EPI == 1) {
#pragma unroll
        for (int t = 0; t < NT; t++)
#pragma unroll
            for (int j = 0; j < 4; j++) {
                float v = fmaxf(acc[t][j] + bias[t * 16 + ecol], 0.f);
                outH[(size_t)(er0 + j) * 128 + t * 16 + ecol] = bf16_rne(v);
            }
    } else {
        float p0[4], p1[4];
#pragma unroll
        for (int j = 0; j < 4; j++) { p0[j] = 0.f; p1[j] = 0.f; }
#pragma unroll
        for (int t = 0; t < NT; t++) {
            int cc = t * 16 + ecol;
            float w0 = wfin[cc * 2 + 0], w1 = wfin[cc * 2 + 1];
#pragma unroll
            for (int j = 0; j < 4; j++) {
                float v = fmaxf(acc[t][j] + bias[cc], 0.f);
                p0[j] = fmaf(v, w0, p0[j]);
                p1[j] = fmaf(v, w1, p1[j]);
            }
        }
#pragma unroll
        for (int m = 1; m < 16; m <<= 1)
#pragma unroll
            for (int j = 0; j < 4; j++) {
                p0[j] += __shfl_xor(p0[j], m, 64);
                p1[j] += __shfl_xor(p1[j], m, 64);
            }
        if (ecol == 0) {
            float b0 = bfin[0], b1 = bfin[1];
#pragma unroll
            for (int j = 0; j < 4; j++) {
                outF[(er0 + j) * 2 + 0] = p0[j] + b0;
                outF[(er0 + j) * 2 + 1] = p1[j] + b1;
            }
        }
    }
}

// ------- fused: per-dst softmax (no-max) + 4-wide ILP aggregate + bias/ReLU/res/LN ----
__global__ __launch_bounds__(256) void gat_agg(
    const unsigned short* __restrict__ hb, const float* __restrict__ a_s,
    const float* __restrict__ a_d, const int* __restrict__ offs,
    const int* __restrict__ col, const float* __restrict__ bgl,
    const float* __restrict__ gl, const float* __restrict__ bl,
    unsigned short* __restrict__ xh, unsigned short* __restrict__ xl)
{
    __shared__ float wsm[4][64][4];
    __shared__ int   ssm[4][64];
    int wv = threadIdx.x >> 6;
    int lane = threadIdx.x & 63;
    int node = blockIdx.x * 4 + wv;
    int s = offs[node], e = offs[node + 1];
    int deg = e - s;
    float4 ad = *(const float4*)(a_d + (size_t)node * 4);

    int c0 = 2 * lane, c1 = 2 * lane + 1;
    int head = lane >> 4;
    float acc0 = 0.f, acc1 = 0.f;
    float den = 1e-16f;

    if (deg <= 64) {
        // all 64 lanes write (zero-pad beyond deg) -> branch-free 4-wide agg loop
        int src = 0;
        float4 wv4 = make_float4(0.f, 0.f, 0.f, 0.f);
        if (lane < deg) {
            src = col[s + lane];
            float4 as = *(const float4*)(a_s + (size_t)src * 4);
            float s0 = as.x + ad.x; s0 = (s0 > 0.f) ? s0 : 0.2f * s0;
            float s1 = as.y + ad.y; s1 = (s1 > 0.f) ? s1 : 0.2f * s1;
            float s2 = as.z + ad.z; s2 = (s2 > 0.f) ? s2 : 0.2f * s2;
            float s3 = as.w + ad.w; s3 = (s3 > 0.f) ? s3 : 0.2f * s3;
            wv4 = make_float4(expf(s0), expf(s1), expf(s2), expf(s3));
        }
        *(float4*)&wsm[wv][lane][0] = wv4;
        ssm[wv][lane] = src;
        // same-wave LDS RAW: no barrier needed. 4-wide: 4 independent gathers in flight.
        int dg4 = (deg + 3) & ~3;
        for (int j = 0; j < dg4; j += 4) {
            int s0 = ssm[wv][j + 0], s1 = ssm[wv][j + 1];
            int s2 = ssm[wv][j + 2], s3 = ssm[wv][j + 3];
            float w0 = wsm[wv][j + 0][head], w1 = wsm[wv][j + 1][head];
            float w2 = wsm[wv][j + 2][head], w3 = wsm[wv][j + 3][head];
            unsigned v0 = *(const unsigned*)(hb + (((unsigned)s0 << 7) + (unsigned)c0));
            unsigned v1 = *(const unsigned*)(hb + (((unsigned)s1 << 7) + (unsigned)c0));
            unsigned v2 = *(const unsigned*)(hb + (((unsigned)s2 << 7) + (unsigned)c0));
            unsigned v3 = *(const unsigned*)(hb + (((unsigned)s3 << 7) + (unsigned)c0));
            den += (w0 + w1) + (w2 + w3);
            acc0 = fmaf(w0, __uint_as_float(v0 << 16), acc0);
            acc1 = fmaf(w0, __uint_as_float(v0 & 0xffff0000u), acc1);
            acc0 = fmaf(w1, __uint_as_float(v1 << 16), acc0);
            acc1 = fmaf(w1, __uint_as_float(v1 & 0xffff0000u), acc1);
            acc0 = fmaf(w2, __uint_as_float(v2 << 16), acc0);
            acc1 = fmaf(w2, __uint_as_float(v2 & 0xffff0000u), acc1);
            acc0 = fmaf(w3, __uint_as_float(v3 << 16), acc0);
            acc1 = fmaf(w3, __uint_as_float(v3 & 0xffff0000u), acc1);
        }
    } else {
        for (int j = s; j < e; j++) {
            int src = col[j];
            float4 as = *(const float4*)(a_s + (size_t)src * 4);
            float sh = (head == 0) ? (as.x + ad.x) : (head == 1) ? (as.y + ad.y)
                     : (head == 2) ? (as.z + ad.z) : (as.w + ad.w);
            sh = (sh > 0.f) ? sh : 0.2f * sh;
            float wj = expf(sh);
            den += wj;
            unsigned hv = *(const unsigned*)(hb + (((unsigned)src << 7) + (unsigned)c0));
            acc0 = fmaf(wj, __uint_as_float(hv << 16), acc0);
            acc1 = fmaf(wj, __uint_as_float(hv & 0xffff0000u), acc1);
        }
    }
    float inv = 1.f / den;
    acc0 *= inv;
    acc1 *= inv;

    // epilogue: + bias, ReLU, residual (xh+xl), LayerNorm, write split x
    float o0 = fmaxf(acc0 + bgl[c0], 0.f);
    float o1 = fmaxf(acc1 + bgl[c1], 0.f);
    size_t xi = (size_t)node * HID;
    unsigned ph = *(const unsigned*)(xh + xi + c0);
    unsigned pl = *(const unsigned*)(xl + xi + c0);
    float x0 = __uint_as_float(ph << 16) + __uint_as_float(pl << 16);
    float x1 = __uint_as_float(ph & 0xffff0000u) + __uint_as_float(pl & 0xffff0000u);
    float t0 = x0 + o0, t1 = x1 + o1;
    float mu = wave_reduce_sum(t0 + t1) * (1.f / 128.f);
    float e0 = t0 - mu, e1 = t1 - mu;
    float var = wave_reduce_sum(e0 * e0 + e1 * e1) * (1.f / 128.f);
    float r = 1.f / sqrtf(var + 1e-5f);
    float r0 = e0 * r * gl[c0] + bl[c0];
    float r1 = e1 * r * gl[c1] + bl[c1];
    unsigned short h0 = bf16_rne(r0), h1 = bf16_rne(r1);
    unsigned short l0 = bf16_rne(r0 - bf2f(h0)), l1 = bf16_rne(r1 - bf2f(h1));
    *(unsigned*)(xh + xi + c0) = (unsigned)h0 | ((unsigned)h1 << 16);
    *(unsigned*)(xl + xi + c0) = (unsigned)l0 | ((unsigned)l1 << 16);
}

// ---------------- value head ----------------
__global__ void pool_sum(const unsigned short* __restrict__ xh,
                         const unsigned short* __restrict__ xl, float* __restrict__ partial) {
    int t = threadIdx.x;
    int base = blockIdx.x * 256;
    float s = 0.f;
    for (int i = 0; i < 256; i++) {
        size_t idx = (size_t)(base + i) * HID + t;
        s += bf2f(xh[idx]) + bf2f(xl[idx]);
    }
    partial[blockIdx.x * 128 + t] = s;
}

__global__ void value_mlp(const float* __restrict__ partial,
                          const float* __restrict__ w1t, const float* __restrict__ b1,
                          const float* __restrict__ w2t, const float* __restrict__ b2,
                          const float* __restrict__ W3, const float* __restrict__ b3,
                          float* __restrict__ out)
{
    __shared__ float p[128], h1[128], h2[64];
    int t = threadIdx.x;   // 128
    float s = 0.f;
    for (int i = 0; i < 256; i++) s += partial[i * 128 + t];
    p[t] = s * (1.f / (float)NNODES);
    __syncthreads();
    float a = b1[t];
    const float4* wr = (const float4*)(w1t + (size_t)t * 128);
#pragma unroll
    for (int k4 = 0; k4 < 32; k4++) {
        float4 w = wr[k4];
        a += p[4 * k4] * w.x + p[4 * k4 + 1] * w.y + p[4 * k4 + 2] * w.z + p[4 * k4 + 3] * w.w;
    }
    h1[t] = fmaxf(a, 0.f);
    __syncthreads();
    if (t < 64) {
        float a2 = b2[t];
        const float4* wr2 = (const float4*)(w2t + (size_t)t * 128);
#pragma unroll
        for (int k4 = 0; k4 < 32; k4++) {
            float4 w = wr2[k4];
            a2 += h1[4 * k4] * w.x + h1[4 * k4 + 1] * w.y + h1[4 * k4 + 2] * w.z + h1[4 * k4 + 3] * w.w;
        }
        h2[t] = fmaxf(a2, 0.f);
    }
    __syncthreads();
    if (t == 0) {
        float v = b3[0];
        for (int k = 0; k < 64; k++) v = fmaf(h2[k], W3[k], v);
        out[NDATA * 2] = v;
    }
}

extern "C" void kernel_launch(void* const* d_in, const int* in_sizes, int n_in,
                              void* d_out, int out_size, void* d_ws, size_t ws_size,
                              hipStream_t stream)
{
    const float* feat  = (const float*)d_in[0];
    const int*   ei    = (const int*)d_in[1];
    const float* W_emb = (const float*)d_in[2];
    const float* b_emb = (const float*)d_in[3];
    const float* ln0g  = (const float*)d_in[4];
    const float* ln0b  = (const float*)d_in[5];
    const float* Wg    = (const float*)d_in[6];
    const float* att_s = (const float*)d_in[7];
    const float* att_d = (const float*)d_in[8];
    const float* bg    = (const float*)d_in[9];
    const float* lng   = (const float*)d_in[10];
    const float* lnb   = (const float*)d_in[11];
    const float* pW1 = (const float*)d_in[12]; const float* pb1 = (const float*)d_in[13];
    const float* pW2 = (const float*)d_in[14]; const float* pb2 = (const float*)d_in[15];
    const float* pW3 = (const float*)d_in[16]; const float* pb3 = (const float*)d_in[17];
    const float* vW1 = (const float*)d_in[18]; const float* vb1 = (const float*)d_in[19];
    const float* vW2 = (const float*)d_in[20]; const float* vb2 = (const float*)d_in[21];
    const float* vW3 = (const float*)d_in[22]; const float* vb3 = (const float*)d_in[23];
    float* out = (float*)d_out;
    int Eo = in_sizes[1] / 2;

    // workspace layout
    unsigned short* xh = (unsigned short*)d_ws;              // 65536*128 bf16
    unsigned short* xl = xh + (size_t)NNODES * HID;
    unsigned short* hb = xl + (size_t)NNODES * HID;          // h bf16; reused as ph1h
    float* a_s = (float*)(hb + (size_t)NNODES * HID);
    float* a_d = a_s + NNODES * HEADS;
    unsigned short* wgt_h = (unsigned short*)(a_d + NNODES * HEADS);  // 4*144*128
    unsigned short* wgt_l = wgt_h + 4 * 144 * 128;
    unsigned short* pw1h  = wgt_l + 4 * 144 * 128;           // 128*128
    unsigned short* pw1l  = pw1h + 128 * 128;
    unsigned short* pw2h  = pw1l + 128 * 128;                // 64*128
    unsigned short* pw2l  = pw2h + 64 * 128;
    float* w1t  = (float*)(pw2l + 64 * 128);                 // 128*128 f32
    float* w2t  = w1t + 128 * 128;                           // 64*128 f32
    float* partial = w2t + 64 * 128;                         // 256*128 f32
    int* deg    = (int*)(partial + 256 * 128);
    int* offs   = deg + NNODES;
    int* cursor = offs + NNODES + 2;
    int* bsum   = cursor + NNODES;
    int* col    = bsum + 256;
    unsigned short* ph1h = hb;

    // weight prep
    prep_wg<<<4 * 144 * 128 / 256, 256, 0, stream>>>(Wg, att_s, att_d, wgt_h, wgt_l);
    prep_heads<<<192, 256, 0, stream>>>(pW1, pW2, vW1, vW2,
                                        pw1h, pw1l, pw2h, pw2l, w1t, w2t);

    // CSR build (dst -> src list), self-loops included (+1 folded into scan1)
    hipMemsetAsync(deg, 0, (size_t)NNODES * 4, stream);
    hist_kernel<<<(Eo + 255) / 256, 256, 0, stream>>>(ei, deg, Eo);
    scan1<<<256, 256, 0, stream>>>(deg, offs, bsum);
    scan2<<<1, 256, 0, stream>>>(bsum);
    scan3<<<256, 256, 0, stream>>>(offs, bsum, cursor, Eo);
    fill_kernel<<<(Eo + NNODES + 255) / 256, 256, 0, stream>>>(ei, cursor, col, Eo);

    // embedding -> xh/xl
    embed_kernel<<<NNODES / 4, 256, 0, stream>>>(feat, W_emb, b_emb, ln0g, ln0b, xh, xl);

    // GAT layers
    for (int l = 0; l < LAYERS; l++) {
        mfma_gemm<9, 0, true><<<NNODES / 128, 512, 0, stream>>>(
            xh, xl, wgt_h + (size_t)l * 144 * 128, wgt_l + (size_t)l * 144 * 128,
            nullptr, hb, a_s, a_d, nullptr, nullptr, nullptr);
        gat_agg<<<NNODES / 4, 256, 0, stream>>>(
            hb, a_s, a_d, offs, col, bg + l * HID, lng + l * HID, lnb + l * HID, xh, xl);
    }

    // policy head: GEMM1 -> bf16-hi ph1; GEMM2 (2-product) + fused [64,2] -> logits
    mfma_gemm<8, 1, true><<<NDATA / 128, 512, 0, stream>>>(
        xh, xl, pw1h, pw1l, pb1, ph1h, nullptr, nullptr, nullptr, nullptr, nullptr);
    mfma_gemm<4, 2, false><<<NDATA / 128, 512, 0, stream>>>(
        ph1h, nullptr, pw2h, pw2l, pb2, nullptr, nullptr, nullptr, pW3, pb3, out);

    // value head
    pool_sum<<<256, 128, 0, stream>>>(xh, xl, partial);
    value_mlp<<<1, 128, 0, stream>>>(partial, w1t, vb1, w2t, vb2, vW3, vb3, out);
}

// Round 10
// 348.581 us; speedup vs baseline: 1.1722x; 1.0306x over previous
//
#include <hip/hip_runtime.h>

#define NNODES 65536
#define NDATA  32768
#define HID    128
#define HEADS  4
#define CHANS  32
#define LAYERS 4

using bf16x8 = __attribute__((ext_vector_type(8))) short;
using f32x4  = __attribute__((ext_vector_type(4))) float;

__device__ __forceinline__ float wave_reduce_sum(float v) {
#pragma unroll
    for (int m = 1; m < 64; m <<= 1) v += __shfl_xor(v, m, 64);
    return v;
}

__device__ __forceinline__ unsigned short bf16_rne(float f) {
    unsigned u = __float_as_uint(f);
    return (unsigned short)((u + 0x7fffu + ((u >> 16) & 1u)) >> 16);
}
__device__ __forceinline__ float bf2f(unsigned short u) {
    return __uint_as_float((unsigned)u << 16);
}

__device__ __forceinline__ void gload_lds16(const unsigned short* g, unsigned short* l) {
    __builtin_amdgcn_global_load_lds(
        (const __attribute__((address_space(1))) void*)g,
        (__attribute__((address_space(3))) void*)l, 16, 0, 0);
}

// ---------------- CSR build ----------------
__global__ void hist_kernel(const int* __restrict__ ei, int* __restrict__ deg, int Eo) {
    int e = blockIdx.x * 256 + threadIdx.x;
    if (e >= Eo) return;
    atomicAdd(&deg[ei[Eo + e]], 1);   // dst row
}

// reads deg+1 (self-loop folded here; deg zeroed by memset)
__global__ void scan1(const int* __restrict__ deg, int* __restrict__ offs, int* __restrict__ bsum) {
    __shared__ int s[256];
    int t = threadIdx.x, b = blockIdx.x;
    int v = deg[b * 256 + t] + 1;
    s[t] = v;
    __syncthreads();
    for (int off = 1; off < 256; off <<= 1) {
        int add = (t >= off) ? s[t - off] : 0;
        __syncthreads();
        s[t] += add;
        __syncthreads();
    }
    offs[b * 256 + t] = s[t] - v;
    if (t == 255) bsum[b] = s[255];
}

__global__ void scan2(int* __restrict__ bsum) {
    __shared__ int s[256];
    int t = threadIdx.x;
    int v = bsum[t];
    s[t] = v;
    __syncthreads();
    for (int off = 1; off < 256; off <<= 1) {
        int add = (t >= off) ? s[t - off] : 0;
        __syncthreads();
        s[t] += add;
        __syncthreads();
    }
    bsum[t] = s[t] - v;
}

__global__ void scan3(int* __restrict__ offs, const int* __restrict__ bsum,
                      int* __restrict__ cursor, int Eo) {
    int i = blockIdx.x * 256 + threadIdx.x;
    int v = offs[i] + bsum[i >> 8];
    offs[i] = v;
    cursor[i] = v;
    if (i == 0) offs[NNODES] = Eo + NNODES;
}

__global__ void fill_kernel(const int* __restrict__ ei, int* __restrict__ cursor,
                            int* __restrict__ col, int Eo) {
    int e = blockIdx.x * 256 + threadIdx.x;
    int Etot = Eo + NNODES;
    if (e >= Etot) return;
    int src, dst;
    if (e < Eo) { src = ei[e]; dst = ei[Eo + e]; }
    else        { src = dst = e - Eo; }
    int pos = atomicAdd(&cursor[dst], 1);
    col[pos] = src;
}

// ------- unified weight prep: GAT (transpose + fused score cols + split + frag-pack),
//         policy (split + frag-pack), value (transpose f32) -------
__global__ void prep_all(const float* __restrict__ Wg, const float* __restrict__ attS,
                         const float* __restrict__ attD,
                         const float* __restrict__ pW1, const float* __restrict__ pW2,
                         const float* __restrict__ vW1, const float* __restrict__ vW2,
                         unsigned short* __restrict__ wh, unsigned short* __restrict__ wl,
                         unsigned short* __restrict__ w1h, unsigned short* __restrict__ w1l,
                         unsigned short* __restrict__ w2h, unsigned short* __restrict__ w2l,
                         float* __restrict__ w1t, float* __restrict__ w2t)
{
    int id = blockIdx.x * 256 + threadIdx.x;
    if (id < 4 * 144 * 128) {
        int l = id / (144 * 128);
        int rem = id % (144 * 128);
        int n = rem / 128, k = rem % 128;
        const float* W = Wg + (size_t)l * HID * HID;
        float v = 0.f;
        if (n < 128) {
            v = W[k * HID + n];
        } else if (n < 136) {
            int h = (n - 128) & 3;
            const float* av = ((n - 128) < 4 ? attS : attD) + l * HID + h * CHANS;
            for (int c = 0; c < CHANS; c++) v += W[k * HID + h * CHANS + c] * av[c];
        }
        unsigned short hh = bf16_rne(v);
        int t = n >> 4, bcol = n & 15;
        int ks = k >> 5, kq = (k >> 3) & 3, e = k & 7;
        size_t o = (size_t)l * (144 * 128) + (size_t)(((t * 4 + ks) * 64) + (kq * 16 + bcol)) * 8 + e;
        wh[o] = hh;
        wl[o] = bf16_rne(v - bf2f(hh));
        return;
    }
    id -= 4 * 144 * 128;
    if (id < 24576) {
        int n, k;
        float v;
        unsigned short *dh, *dl;
        if (id < 16384) {
            n = id / 128; k = id % 128;
            v = pW1[k * 128 + n];
            dh = w1h; dl = w1l;
        } else {
            int j = id - 16384;
            n = j / 128; k = j % 128;
            v = pW2[k * 64 + n];
            dh = w2h; dl = w2l;
        }
        unsigned short hh = bf16_rne(v);
        int t = n >> 4, bcol = n & 15;
        int ks = k >> 5, kq = (k >> 3) & 3, e = k & 7;
        size_t o = (size_t)(((t * 4 + ks) * 64) + (kq * 16 + bcol)) * 8 + e;
        dh[o] = hh;
        dl[o] = bf16_rne(v - bf2f(hh));
        return;
    }
    id -= 24576;
    if (id < 16384) {
        int t = id >> 7, k = id & 127;
        w1t[t * 128 + k] = vW1[k * 128 + t];
    } else if (id < 24576) {
        int j = id - 16384;
        int t = j >> 7, k = j & 127;
        w2t[t * 128 + k] = vW2[k * 64 + t];
    }
}

// ---------------- embedding + LN + ReLU -> xh/xl split (warp per node) ----------------
__global__ __launch_bounds__(256) void embed_kernel(
    const float* __restrict__ feat, const float* __restrict__ W,
    const float* __restrict__ bb, const float* __restrict__ g,
    const float* __restrict__ be, unsigned short* __restrict__ xh,
    unsigned short* __restrict__ xl)
{
    int node = blockIdx.x * 4 + (threadIdx.x >> 6);
    int lane = threadIdx.x & 63;
    float f[10];
#pragma unroll
    for (int i = 0; i < 10; i++) f[i] = feat[node * 10 + i];
    int c0 = 2 * lane, c1 = c0 + 1;
    float v0 = bb[c0], v1 = bb[c1];
#pragma unroll
    for (int i = 0; i < 10; i++) {
        v0 = fmaf(f[i], W[i * HID + c0], v0);
        v1 = fmaf(f[i], W[i * HID + c1], v1);
    }
    float mu = wave_reduce_sum(v0 + v1) * (1.f / 128.f);
    float e0 = v0 - mu, e1 = v1 - mu;
    float var = wave_reduce_sum(e0 * e0 + e1 * e1) * (1.f / 128.f);
    float r = 1.f / sqrtf(var + 1e-5f);
    float r0 = fmaxf(e0 * r * g[c0] + be[c0], 0.f);
    float r1 = fmaxf(e1 * r * g[c1] + be[c1], 0.f);
    unsigned short h0 = bf16_rne(r0), h1 = bf16_rne(r1);
    unsigned short l0 = bf16_rne(r0 - bf2f(h0)), l1 = bf16_rne(r1 - bf2f(h1));
    size_t xi = (size_t)node * HID;
    *(unsigned*)(xh + xi + c0) = (unsigned)h0 | ((unsigned)h1 << 16);
    *(unsigned*)(xl + xi + c0) = (unsigned)l0 | ((unsigned)l1 << 16);
}

// ---------------- MFMA GEMM, K=128, 2-product (Ah*Bh + Ah*Bl) ----
// A read as bf16-hi only (error == hb's own bf16 rounding); B keeps full hi/lo split.
// 512 thr = 8 waves; BM=128; B staged via global_load_lds in 2 K-phases.
// EPI 0: GAT (tiles 0..7 -> hb bf16; tile 8 cols 0..3 -> a_s, 4..7 -> a_d)
// EPI 1: bias+relu -> bf16 outH (hi only)
// EPI 2: bias+relu + fused final layer [64]x[64,2] -> logits (shfl-reduce)
template <int NT, int EPI>
__global__ __launch_bounds__(512, 4) void mfma_gemm(
    const unsigned short* __restrict__ Ah,
    const unsigned short* __restrict__ Bh, const unsigned short* __restrict__ Bl,
    const float* __restrict__ bias,
    unsigned short* __restrict__ outH,
    float* __restrict__ a_s, float* __restrict__ a_d,
    const float* __restrict__ wfin, const float* __restrict__ bfin,
    float* __restrict__ outF)
{
    __shared__ unsigned short lds[NT * 2048];

    int tid = threadIdx.x;
    int wid = tid >> 6, l = tid & 63;
    int row = blockIdx.x * 128 + wid * 16 + (l & 15);
    int kg = (l >> 4) * 8;

    const unsigned short* arh = Ah + (size_t)row * 128 + kg;
    bf16x8 afh[4];
#pragma unroll
    for (int ks = 0; ks < 4; ks++) afh[ks] = *(const bf16x8*)(arh + ks * 32);

    f32x4 acc[NT];
#pragma unroll
    for (int t = 0; t < NT; t++) acc[t] = (f32x4){0.f, 0.f, 0.f, 0.f};

#pragma unroll
    for (int p = 0; p < 2; p++) {
        __syncthreads();   // all waves done reading previous LDS contents
        for (int c = wid; c < 4 * NT; c += 8) {
            int fr = c >> 1, lo = c & 1;
            int t = fr >> 1, ksl = fr & 1;
            const unsigned short* src = (lo ? Bl : Bh)
                + ((size_t)(t * 4 + p * 2 + ksl) << 9) + ((unsigned)l << 3);
            gload_lds16(src, &lds[(size_t)c << 9]);
        }
        __syncthreads();   // drains vmcnt (global_load_lds) before reads
#pragma unroll
        for (int ksl = 0; ksl < 2; ksl++) {
            int ks = p * 2 + ksl;
#pragma unroll
            for (int t = 0; t < NT; t++) {
                const unsigned short* bp = &lds[(((t * 2 + ksl) << 1) << 9) + (l << 3)];
                bf16x8 bh  = *(const bf16x8*)bp;
                bf16x8 blo = *(const bf16x8*)(bp + 512);
                acc[t] = __builtin_amdgcn_mfma_f32_16x16x32_bf16(afh[ks], bh,  acc[t], 0, 0, 0);
                acc[t] = __builtin_amdgcn_mfma_f32_16x16x32_bf16(afh[ks], blo, acc[t], 0, 0, 0);
            }
        }
    }

    // C/D layout: col = lane&15, row = (lane>>4)*4 + reg   [HW-verified]
    int ecol = l & 15;
    int er0 = blockIdx.x * 128 + wid * 16 + ((l >> 4) << 2);

    if constexpr (EPI == 0) {
#pragma unroll
        for (int t = 0; t < 8; t++)
#pragma unroll
            for (int j = 0; j < 4; j++)
                outH[(size_t)(er0 + j) * 128 + t * 16 + ecol] = bf16_rne(acc[t][j]);
#pragma unroll
        for (int j = 0; j < 4; j++) {
            float v = acc[8][j];
            if (ecol < 4)      a_s[(er0 + j) * 4 + ecol] = v;
            else if (ecol < 8) a_d[(er0 + j) * 4 + (ecol - 4)] = v;
        }
    } else if constexpr (EPI == 1) {
#pragma unroll
        for (int t = 0; t < NT; t++)
#pragma unroll
            for (int j = 0; j < 4; j++) {
                float v = fmaxf(acc[t][j] + bias[t * 16 + ecol], 0.f);
                outH[(size_t)(er0 + j) * 128 + t * 16 + ecol] = bf16_rne(v);
            }
    } else {
        float p0[4], p1[4];
#pragma unroll
        for (int j = 0; j < 4; j++) { p0[j] = 0.f; p1[j] = 0.f; }
#pragma unroll
        for (int t = 0; t < NT; t++) {
            int cc = t * 16 + ecol;
            float w0 = wfin[cc * 2 + 0], w1 = wfin[cc * 2 + 1];
#pragma unroll
            for (int j = 0; j < 4; j++) {
                float v = fmaxf(acc[t][j] + bias[cc], 0.f);
                p0[j] = fmaf(v, w0, p0[j]);
                p1[j] = fmaf(v, w1, p1[j]);
            }
        }
#pragma unroll
        for (int m = 1; m < 16; m <<= 1)
#pragma unroll
            for (int j = 0; j < 4; j++) {
                p0[j] += __shfl_xor(p0[j], m, 64);
                p1[j] += __shfl_xor(p1[j], m, 64);
            }
        if (ecol == 0) {
            float b0 = bfin[0], b1 = bfin[1];
#pragma unroll
            for (int j = 0; j < 4; j++) {
                outF[(er0 + j) * 2 + 0] = p0[j] + b0;
                outF[(er0 + j) * 2 + 1] = p1[j] + b1;
            }
        }
    }
}

// ------- fused: per-dst softmax (no-max, __expf) + 4-wide ILP aggregate + epilogue ----
__global__ __launch_bounds__(256) void gat_agg(
    const unsigned short* __restrict__ hb, const float* __restrict__ a_s,
    const float* __restrict__ a_d, const int* __restrict__ offs,
    const int* __restrict__ col, const float* __restrict__ bgl,
    const float* __restrict__ gl, const float* __restrict__ bl,
    unsigned short* __restrict__ xh, unsigned short* __restrict__ xl)
{
    __shared__ int2 whs[4][4][64];   // [wave][head][edge] = {w_bits, src}
    int wv = threadIdx.x >> 6;
    int lane = threadIdx.x & 63;
    int node = blockIdx.x * 4 + wv;
    int s = offs[node], e = offs[node + 1];
    int deg = e - s;
    float4 ad = *(const float4*)(a_d + (size_t)node * 4);

    int c0 = 2 * lane, c1 = 2 * lane + 1;
    int head = lane >> 4;
    float acc0 = 0.f, acc1 = 0.f;
    float den = 1e-16f;

    if (deg <= 64) {
        // all 64 lanes write (zero-pad beyond deg) -> branch-free 4-wide agg loop
        int src = 0;
        float e0 = 0.f, e1 = 0.f, e2 = 0.f, e3 = 0.f;
        if (lane < deg) {
            src = col[s + lane];
            float4 as = *(const float4*)(a_s + (size_t)src * 4);
            float s0 = as.x + ad.x; s0 = fmaxf(s0, 0.2f * s0);
            float s1 = as.y + ad.y; s1 = fmaxf(s1, 0.2f * s1);
            float s2 = as.z + ad.z; s2 = fmaxf(s2, 0.2f * s2);
            float s3 = as.w + ad.w; s3 = fmaxf(s3, 0.2f * s3);
            e0 = __expf(s0); e1 = __expf(s1); e2 = __expf(s2); e3 = __expf(s3);
        }
        whs[wv][0][lane] = make_int2(__float_as_int(e0), src);
        whs[wv][1][lane] = make_int2(__float_as_int(e1), src);
        whs[wv][2][lane] = make_int2(__float_as_int(e2), src);
        whs[wv][3][lane] = make_int2(__float_as_int(e3), src);
        // same-wave LDS RAW: no barrier needed. 4-wide: 4 independent gathers in flight.
        const int2* wrow = &whs[wv][head][0];
        int dg4 = (deg + 3) & ~3;
        for (int j = 0; j < dg4; j += 4) {
            int2 q0 = wrow[j + 0], q1 = wrow[j + 1];
            int2 q2 = wrow[j + 2], q3 = wrow[j + 3];
            float w0 = __int_as_float(q0.x), w1 = __int_as_float(q1.x);
            float w2 = __int_as_float(q2.x), w3 = __int_as_float(q3.x);
            unsigned v0 = *(const unsigned*)(hb + (((unsigned)q0.y << 7) + (unsigned)c0));
            unsigned v1 = *(const unsigned*)(hb + (((unsigned)q1.y << 7) + (unsigned)c0));
            unsigned v2 = *(const unsigned*)(hb + (((unsigned)q2.y << 7) + (unsigned)c0));
            unsigned v3 = *(const unsigned*)(hb + (((unsigned)q3.y << 7) + (unsigned)c0));
            den += (w0 + w1) + (w2 + w3);
            acc0 = fmaf(w0, __uint_as_float(v0 << 16), acc0);
            acc1 = fmaf(w0, __uint_as_float(v0 & 0xffff0000u), acc1);
            acc0 = fmaf(w1, __uint_as_float(v1 << 16), acc0);
            acc1 = fmaf(w1, __uint_as_float(v1 & 0xffff0000u), acc1);
            acc0 = fmaf(w2, __uint_as_float(v2 << 16), acc0);
            acc1 = fmaf(w2, __uint_as_float(v2 & 0xffff0000u), acc1);
            acc0 = fmaf(w3, __uint_as_float(v3 << 16), acc0);
            acc1 = fmaf(w3, __uint_as_float(v3 & 0xffff0000u), acc1);
        }
    } else {
        for (int j = s; j < e; j++) {
            int src = col[j];
            float4 as = *(const float4*)(a_s + (size_t)src * 4);
            float sh = (head == 0) ? (as.x + ad.x) : (head == 1) ? (as.y + ad.y)
                     : (head == 2) ? (as.z + ad.z) : (as.w + ad.w);
            sh = fmaxf(sh, 0.2f * sh);
            float wj = __expf(sh);
            den += wj;
            unsigned hv = *(const unsigned*)(hb + (((unsigned)src << 7) + (unsigned)c0));
            acc0 = fmaf(wj, __uint_as_float(hv << 16), acc0);
            acc1 = fmaf(wj, __uint_as_float(hv & 0xffff0000u), acc1);
        }
    }
    float inv = 1.f / den;
    acc0 *= inv;
    acc1 *= inv;

    // epilogue: + bias, ReLU, residual (xh+xl), LayerNorm, write split x
    float o0 = fmaxf(acc0 + bgl[c0], 0.f);
    float o1 = fmaxf(acc1 + bgl[c1], 0.f);
    size_t xi = (size_t)node * HID;
    unsigned ph = *(const unsigned*)(xh + xi + c0);
    unsigned pl = *(const unsigned*)(xl + xi + c0);
    float x0 = __uint_as_float(ph << 16) + __uint_as_float(pl << 16);
    float x1 = __uint_as_float(ph & 0xffff0000u) + __uint_as_float(pl & 0xffff0000u);
    float t0 = x0 + o0, t1 = x1 + o1;
    float mu = wave_reduce_sum(t0 + t1) * (1.f / 128.f);
    float e0 = t0 - mu, e1 = t1 - mu;
    float var = wave_reduce_sum(e0 * e0 + e1 * e1) * (1.f / 128.f);
    float r = 1.f / sqrtf(var + 1e-5f);
    float r0 = e0 * r * gl[c0] + bl[c0];
    float r1 = e1 * r * gl[c1] + bl[c1];
    unsigned short h0 = bf16_rne(r0), h1 = bf16_rne(r1);
    unsigned short l0 = bf16_rne(r0 - bf2f(h0)), l1 = bf16_rne(r1 - bf2f(h1));
    *(unsigned*)(xh + xi + c0) = (unsigned)h0 | ((unsigned)h1 << 16);
    *(unsigned*)(xl + xi + c0) = (unsigned)l0 | ((unsigned)l1 << 16);
}

// ---------------- value head ----------------
__global__ void pool_sum(const unsigned short* __restrict__ xh,
                         const unsigned short* __restrict__ xl, float* __restrict__ partial) {
    int t = threadIdx.x;
    int base = blockIdx.x * 256;
    float s = 0.f;
    for (int i = 0; i < 256; i++) {
        size_t idx = (size_t)(base + i) * HID + t;
        s += bf2f(xh[idx]) + bf2f(xl[idx]);
    }
    partial[blockIdx.x * 128 + t] = s;
}

__global__ void value_mlp(const float* __restrict__ partial,
                          const float* __restrict__ w1t, const float* __restrict__ b1,
                          const float* __restrict__ w2t, const float* __restrict__ b2,
                          const float* __restrict__ W3, const float* __restrict__ b3,
                          float* __restrict__ out)
{
    __shared__ float p[128], h1[128], h2[64];
    int t = threadIdx.x;   // 128
    float s = 0.f;
    for (int i = 0; i < 256; i++) s += partial[i * 128 + t];
    p[t] = s * (1.f / (float)NNODES);
    __syncthreads();
    float a = b1[t];
    const float4* wr = (const float4*)(w1t + (size_t)t * 128);
#pragma unroll
    for (int k4 = 0; k4 < 32; k4++) {
        float4 w = wr[k4];
        a += p[4 * k4] * w.x + p[4 * k4 + 1] * w.y + p[4 * k4 + 2] * w.z + p[4 * k4 + 3] * w.w;
    }
    h1[t] = fmaxf(a, 0.f);
    __syncthreads();
    if (t < 64) {
        float a2 = b2[t];
        const float4* wr2 = (const float4*)(w2t + (size_t)t * 128);
#pragma unroll
        for (int k4 = 0; k4 < 32; k4++) {
            float4 w = wr2[k4];
            a2 += h1[4 * k4] * w.x + h1[4 * k4 + 1] * w.y + h1[4 * k4 + 2] * w.z + h1[4 * k4 + 3] * w.w;
        }
        h2[t] = fmaxf(a2, 0.f);
    }
    __syncthreads();
    if (t == 0) {
        float v = b3[0];
        for (int k = 0; k < 64; k++) v = fmaf(h2[k], W3[k], v);
        out[NDATA * 2] = v;
    }
}

extern "C" void kernel_launch(void* const* d_in, const int* in_sizes, int n_in,
                              void* d_out, int out_size, void* d_ws, size_t ws_size,
                              hipStream_t stream)
{
    const float* feat  = (const float*)d_in[0];
    const int*   ei    = (const int*)d_in[1];
    const float* W_emb = (const float*)d_in[2];
    const float* b_emb = (const float*)d_in[3];
    const float* ln0g  = (const float*)d_in[4];
    const float* ln0b  = (const float*)d_in[5];
    const float* Wg    = (const float*)d_in[6];
    const float* att_s = (const float*)d_in[7];
    const float* att_d = (const float*)d_in[8];
    const float* bg    = (const float*)d_in[9];
    const float* lng   = (const float*)d_in[10];
    const float* lnb   = (const float*)d_in[11];
    const float* pW1 = (const float*)d_in[12]; const float* pb1 = (const float*)d_in[13];
    const float* pW2 = (const float*)d_in[14]; const float* pb2 = (const float*)d_in[15];
    const float* pW3 = (const float*)d_in[16]; const float* pb3 = (const float*)d_in[17];
    const float* vW1 = (const float*)d_in[18]; const float* vb1 = (const float*)d_in[19];
    const float* vW2 = (const float*)d_in[20]; const float* vb2 = (const float*)d_in[21];
    const float* vW3 = (const float*)d_in[22]; const float* vb3 = (const float*)d_in[23];
    float* out = (float*)d_out;
    int Eo = in_sizes[1] / 2;

    // workspace layout
    unsigned short* xh = (unsigned short*)d_ws;              // 65536*128 bf16
    unsigned short* xl = xh + (size_t)NNODES * HID;
    unsigned short* hb = xl + (size_t)NNODES * HID;          // h bf16; reused as ph1h
    float* a_s = (float*)(hb + (size_t)NNODES * HID);
    float* a_d = a_s + NNODES * HEADS;
    unsigned short* wgt_h = (unsigned short*)(a_d + NNODES * HEADS);  // 4*144*128
    unsigned short* wgt_l = wgt_h + 4 * 144 * 128;
    unsigned short* pw1h  = wgt_l + 4 * 144 * 128;           // 128*128
    unsigned short* pw1l  = pw1h + 128 * 128;
    unsigned short* pw2h  = pw1l + 128 * 128;                // 64*128
    unsigned short* pw2l  = pw2h + 64 * 128;
    float* w1t  = (float*)(pw2l + 64 * 128);                 // 128*128 f32
    float* w2t  = w1t + 128 * 128;                           // 64*128 f32
    float* partial = w2t + 64 * 128;                         // 256*128 f32
    int* deg    = (int*)(partial + 256 * 128);
    int* offs   = deg + NNODES;
    int* cursor = offs + NNODES + 2;
    int* bsum   = cursor + NNODES;
    int* col    = bsum + 256;
    unsigned short* ph1h = hb;

    // unified weight prep (GAT + policy + value)
    prep_all<<<(4 * 144 * 128 + 24576 + 24576) / 256, 256, 0, stream>>>(
        Wg, att_s, att_d, pW1, pW2, vW1, vW2,
        wgt_h, wgt_l, pw1h, pw1l, pw2h, pw2l, w1t, w2t);

    // CSR build (dst -> src list), self-loops included (+1 folded into scan1)
    hipMemsetAsync(deg, 0, (size_t)NNODES * 4, stream);
    hist_kernel<<<(Eo + 255) / 256, 256, 0, stream>>>(ei, deg, Eo);
    scan1<<<256, 256, 0, stream>>>(deg, offs, bsum);
    scan2<<<1, 256, 0, stream>>>(bsum);
    scan3<<<256, 256, 0, stream>>>(offs, bsum, cursor, Eo);
    fill_kernel<<<(Eo + NNODES + 255) / 256, 256, 0, stream>>>(ei, cursor, col, Eo);

    // embedding -> xh/xl
    embed_kernel<<<NNODES / 4, 256, 0, stream>>>(feat, W_emb, b_emb, ln0g, ln0b, xh, xl);

    // GAT layers
    for (int l = 0; l < LAYERS; l++) {
        mfma_gemm<9, 0><<<NNODES / 128, 512, 0, stream>>>(
            xh, wgt_h + (size_t)l * 144 * 128, wgt_l + (size_t)l * 144 * 128,
            nullptr, hb, a_s, a_d, nullptr, nullptr, nullptr);
        gat_agg<<<NNODES / 4, 256, 0, stream>>>(
            hb, a_s, a_d, offs, col, bg + l * HID, lng + l * HID, lnb + l * HID, xh, xl);
    }

    // policy head: GEMM1 -> bf16-hi ph1; GEMM2 + fused [64,2] -> logits
    mfma_gemm<8, 1><<<NDATA / 128, 512, 0, stream>>>(
        xh, pw1h, pw1l, pb1, ph1h, nullptr, nullptr, nullptr, nullptr, nullptr);
    mfma_gemm<4, 2><<<NDATA / 128, 512, 0, stream>>>(
        ph1h, pw2h, pw2l, pb2, nullptr, nullptr, nullptr, pW3, pb3, out);

    // value head
    pool_sum<<<256, 128, 0, stream>>>(xh, xl, partial);
    value_mlp<<<1, 128, 0, stream>>>(partial, w1t, vb1, w2t, vb2, vW3, vb3, out);
}

// Round 11
// 330.557 us; speedup vs baseline: 1.2362x; 1.0545x over previous
//
#include <hip/hip_runtime.h>

#define NNODES 65536
#define NDATA  32768
#define HID    128
#define HEADS  4
#define CHANS  32
#define LAYERS 4

using bf16x8 = __attribute__((ext_vector_type(8))) short;
using f32x4  = __attribute__((ext_vector_type(4))) float;

__device__ __forceinline__ float wave_reduce_sum(float v) {
#pragma unroll
    for (int m = 1; m < 64; m <<= 1) v += __shfl_xor(v, m, 64);
    return v;
}

__device__ __forceinline__ int wave_reduce_sum_i(int v) {
#pragma unroll
    for (int m = 1; m < 64; m <<= 1) v += __shfl_xor(v, m, 64);
    return v;
}

__device__ __forceinline__ unsigned short bf16_rne(float f) {
    unsigned u = __float_as_uint(f);
    return (unsigned short)((u + 0x7fffu + ((u >> 16) & 1u)) >> 16);
}
__device__ __forceinline__ float bf2f(unsigned short u) {
    return __uint_as_float((unsigned)u << 16);
}

__device__ __forceinline__ void gload_lds16(const unsigned short* g, unsigned short* l) {
    __builtin_amdgcn_global_load_lds(
        (const __attribute__((address_space(1))) void*)g,
        (__attribute__((address_space(3))) void*)l, 16, 0, 0);
}

// ---------------- CSR build ----------------
__global__ void hist_kernel(const int* __restrict__ ei, int* __restrict__ deg, int Eo) {
    int e = blockIdx.x * 256 + threadIdx.x;
    if (e >= Eo) return;
    atomicAdd(&deg[ei[Eo + e]], 1);   // dst row
}

// reads deg+1 (self-loop folded here; deg zeroed by memset)
__global__ void scan1(const int* __restrict__ deg, int* __restrict__ offs, int* __restrict__ bsum) {
    __shared__ int s[256];
    int t = threadIdx.x, b = blockIdx.x;
    int v = deg[b * 256 + t] + 1;
    s[t] = v;
    __syncthreads();
    for (int off = 1; off < 256; off <<= 1) {
        int add = (t >= off) ? s[t - off] : 0;
        __syncthreads();
        s[t] += add;
        __syncthreads();
    }
    offs[b * 256 + t] = s[t] - v;
    if (t == 255) bsum[b] = s[255];
}

// scan2 folded in: block b reduces bsum[0..b-1] itself (256 threads, masked)
__global__ void scan3(int* __restrict__ offs, const int* __restrict__ bsum,
                      int* __restrict__ cursor, int Eo) {
    __shared__ int ws[4];
    int b = blockIdx.x, t = threadIdx.x;
    int v = (t < b) ? bsum[t] : 0;
    v = wave_reduce_sum_i(v);
    if ((t & 63) == 0) ws[t >> 6] = v;
    __syncthreads();
    int base = ws[0] + ws[1] + ws[2] + ws[3];
    int i = b * 256 + t;
    int o = offs[i] + base;
    offs[i] = o;
    cursor[i] = o;
    if (i == 0) offs[NNODES] = Eo + NNODES;
}

__global__ void fill_kernel(const int* __restrict__ ei, int* __restrict__ cursor,
                            int* __restrict__ col, int Eo) {
    int e = blockIdx.x * 256 + threadIdx.x;
    int Etot = Eo + NNODES;
    if (e >= Etot) return;
    int src, dst;
    if (e < Eo) { src = ei[e]; dst = ei[Eo + e]; }
    else        { src = dst = e - Eo; }
    int pos = atomicAdd(&cursor[dst], 1);
    col[pos] = src;
}

// ------- merged: embedding (blocks 0..16383) + all weight prep (blocks 16384..) -------
__global__ __launch_bounds__(256) void prep_embed(
    const float* __restrict__ feat, const float* __restrict__ W_emb,
    const float* __restrict__ b_emb, const float* __restrict__ ln0g,
    const float* __restrict__ ln0b, unsigned short* __restrict__ xh,
    const float* __restrict__ Wg, const float* __restrict__ attS,
    const float* __restrict__ attD,
    const float* __restrict__ pW1, const float* __restrict__ pW2,
    const float* __restrict__ vW1, const float* __restrict__ vW2,
    unsigned short* __restrict__ wh, unsigned short* __restrict__ wl,
    unsigned short* __restrict__ w1h, unsigned short* __restrict__ w1l,
    unsigned short* __restrict__ w2h, unsigned short* __restrict__ w2l,
    float* __restrict__ w1t, float* __restrict__ w2t)
{
    if (blockIdx.x < NNODES / 4) {
        // ---- embedding + LN + ReLU -> xh (bf16) ----
        int node = blockIdx.x * 4 + (threadIdx.x >> 6);
        int lane = threadIdx.x & 63;
        float f[10];
#pragma unroll
        for (int i = 0; i < 10; i++) f[i] = feat[node * 10 + i];
        int c0 = 2 * lane, c1 = c0 + 1;
        float v0 = b_emb[c0], v1 = b_emb[c1];
#pragma unroll
        for (int i = 0; i < 10; i++) {
            v0 = fmaf(f[i], W_emb[i * HID + c0], v0);
            v1 = fmaf(f[i], W_emb[i * HID + c1], v1);
        }
        float mu = wave_reduce_sum(v0 + v1) * (1.f / 128.f);
        float e0 = v0 - mu, e1 = v1 - mu;
        float var = wave_reduce_sum(e0 * e0 + e1 * e1) * (1.f / 128.f);
        float r = 1.f / sqrtf(var + 1e-5f);
        float r0 = fmaxf(e0 * r * ln0g[c0] + ln0b[c0], 0.f);
        float r1 = fmaxf(e1 * r * ln0g[c1] + ln0b[c1], 0.f);
        *(unsigned*)(xh + (size_t)node * HID + c0) =
            (unsigned)bf16_rne(r0) | ((unsigned)bf16_rne(r1) << 16);
        return;
    }
    int id = (blockIdx.x - NNODES / 4) * 256 + threadIdx.x;
    if (id < 4 * 144 * 128) {
        int l = id / (144 * 128);
        int rem = id % (144 * 128);
        int n = rem / 128, k = rem % 128;
        const float* W = Wg + (size_t)l * HID * HID;
        float v = 0.f;
        if (n < 128) {
            v = W[k * HID + n];
        } else if (n < 136) {
            int h = (n - 128) & 3;
            const float* av = ((n - 128) < 4 ? attS : attD) + l * HID + h * CHANS;
            for (int c = 0; c < CHANS; c++) v += W[k * HID + h * CHANS + c] * av[c];
        }
        unsigned short hh = bf16_rne(v);
        int t = n >> 4, bcol = n & 15;
        int ks = k >> 5, kq = (k >> 3) & 3, e = k & 7;
        size_t o = (size_t)l * (144 * 128) + (size_t)(((t * 4 + ks) * 64) + (kq * 16 + bcol)) * 8 + e;
        wh[o] = hh;
        wl[o] = bf16_rne(v - bf2f(hh));
        return;
    }
    id -= 4 * 144 * 128;
    if (id < 24576) {
        int n, k;
        float v;
        unsigned short *dh, *dl;
        if (id < 16384) {
            n = id / 128; k = id % 128;
            v = pW1[k * 128 + n];
            dh = w1h; dl = w1l;
        } else {
            int j = id - 16384;
            n = j / 128; k = j % 128;
            v = pW2[k * 64 + n];
            dh = w2h; dl = w2l;
        }
        unsigned short hh = bf16_rne(v);
        int t = n >> 4, bcol = n & 15;
        int ks = k >> 5, kq = (k >> 3) & 3, e = k & 7;
        size_t o = (size_t)(((t * 4 + ks) * 64) + (kq * 16 + bcol)) * 8 + e;
        dh[o] = hh;
        dl[o] = bf16_rne(v - bf2f(hh));
        return;
    }
    id -= 24576;
    if (id < 16384) {
        int t = id >> 7, k = id & 127;
        w1t[t * 128 + k] = vW1[k * 128 + t];
    } else if (id < 24576) {
        int j = id - 16384;
        int t = j >> 7, k = j & 127;
        w2t[t * 128 + k] = vW2[k * 64 + t];
    }
}

// ---------------- MFMA GEMM, K=128, 2-product (Ah*Bh + Ah*Bl) ----
// A read as bf16-hi only; B keeps full hi/lo split.
// 512 thr = 8 waves; BM=128; B staged via global_load_lds in 2 K-phases.
// EPI 0: GAT (tiles 0..7 -> hb bf16; tile 8 cols 0..3 -> a_s, 4..7 -> a_d)
// EPI 1: bias+relu -> bf16 outH
// EPI 2: bias+relu + fused final layer [64]x[64,2] -> logits (shfl-reduce)
template <int NT, int EPI>
__global__ __launch_bounds__(512, 4) void mfma_gemm(
    const unsigned short* __restrict__ Ah,
    const unsigned short* __restrict__ Bh, const unsigned short* __restrict__ Bl,
    const float* __restrict__ bias,
    unsigned short* __restrict__ outH,
    float* __restrict__ a_s, float* __restrict__ a_d,
    const float* __restrict__ wfin, const float* __restrict__ bfin,
    float* __restrict__ outF)
{
    __shared__ unsigned short lds[NT * 2048];

    int tid = threadIdx.x;
    int wid = tid >> 6, l = tid & 63;
    int row = blockIdx.x * 128 + wid * 16 + (l & 15);
    int kg = (l >> 4) * 8;

    const unsigned short* arh = Ah + (size_t)row * 128 + kg;
    bf16x8 afh[4];
#pragma unroll
    for (int ks = 0; ks < 4; ks++) afh[ks] = *(const bf16x8*)(arh + ks * 32);

    f32x4 acc[NT];
#pragma unroll
    for (int t = 0; t < NT; t++) acc[t] = (f32x4){0.f, 0.f, 0.f, 0.f};

#pragma unroll
    for (int p = 0; p < 2; p++) {
        __syncthreads();   // all waves done reading previous LDS contents
        for (int c = wid; c < 4 * NT; c += 8) {
            int fr = c >> 1, lo = c & 1;
            int t = fr >> 1, ksl = fr & 1;
            const unsigned short* src = (lo ? Bl : Bh)
                + ((size_t)(t * 4 + p * 2 + ksl) << 9) + ((unsigned)l << 3);
            gload_lds16(src, &lds[(size_t)c << 9]);
        }
        __syncthreads();   // drains vmcnt (global_load_lds) before reads
#pragma unroll
        for (int ksl = 0; ksl < 2; ksl++) {
            int ks = p * 2 + ksl;
#pragma unroll
            for (int t = 0; t < NT; t++) {
                const unsigned short* bp = &lds[(((t * 2 + ksl) << 1) << 9) + (l << 3)];
                bf16x8 bh  = *(const bf16x8*)bp;
                bf16x8 blo = *(const bf16x8*)(bp + 512);
                acc[t] = __builtin_amdgcn_mfma_f32_16x16x32_bf16(afh[ks], bh,  acc[t], 0, 0, 0);
                acc[t] = __builtin_amdgcn_mfma_f32_16x16x32_bf16(afh[ks], blo, acc[t], 0, 0, 0);
            }
        }
    }

    // C/D layout: col = lane&15, row = (lane>>4)*4 + reg   [HW-verified]
    int ecol = l & 15;
    int er0 = blockIdx.x * 128 + wid * 16 + ((l >> 4) << 2);

    if constexpr (EPI == 0) {
#pragma unroll
        for (int t = 0; t < 8; t++)
#pragma unroll
            for (int j = 0; j < 4; j++)
                outH[(size_t)(er0 + j) * 128 + t * 16 + ecol] = bf16_rne(acc[t][j]);
#pragma unroll
        for (int j = 0; j < 4; j++) {
            float v = acc[8][j];
            if (ecol < 4)      a_s[(er0 + j) * 4 + ecol] = v;
            else if (ecol < 8) a_d[(er0 + j) * 4 + (ecol - 4)] = v;
        }
    } else if constexpr (EPI == 1) {
#pragma unroll
        for (int t = 0; t < NT; t++)
#pragma unroll
            for (int j = 0; j < 4; j++) {
                float v = fmaxf(acc[t][j] + bias[t * 16 + ecol], 0.f);
                outH[(size_t)(er0 + j) * 128 + t * 16 + ecol] = bf16_rne(v);
            }
    } else {
        float p0[4], p1[4];
#pragma unroll
        for (int j = 0; j < 4; j++) { p0[j] = 0.f; p1[j] = 0.f; }
#pragma unroll
        for (int t = 0; t < NT; t++) {
            int cc = t * 16 + ecol;
            float w0 = wfin[cc * 2 + 0], w1 = wfin[cc * 2 + 1];
#pragma unroll
            for (int j = 0; j < 4; j++) {
                float v = fmaxf(acc[t][j] + bias[cc], 0.f);
                p0[j] = fmaf(v, w0, p0[j]);
                p1[j] = fmaf(v, w1, p1[j]);
            }
        }
#pragma unroll
        for (int m = 1; m < 16; m <<= 1)
#pragma unroll
            for (int j = 0; j < 4; j++) {
                p0[j] += __shfl_xor(p0[j], m, 64);
                p1[j] += __shfl_xor(p1[j], m, 64);
            }
        if (ecol == 0) {
            float b0 = bfin[0], b1 = bfin[1];
#pragma unroll
            for (int j = 0; j < 4; j++) {
                outF[(er0 + j) * 2 + 0] = p0[j] + b0;
                outF[(er0 + j) * 2 + 1] = p1[j] + b1;
            }
        }
    }
}

// ------- fused: per-dst softmax (no-max, __expf) + 4-wide ILP aggregate + epilogue ----
// x is bf16-hi only (residual/LN precision: bf16 rounding ~2e-3, amplified ~0.23x per
// policy layer -> ~3e-5 logit error; GEMM inputs already bf16-hi so h/scores unchanged)
__global__ __launch_bounds__(256) void gat_agg(
    const unsigned short* __restrict__ hb, const float* __restrict__ a_s,
    const float* __restrict__ a_d, const int* __restrict__ offs,
    const int* __restrict__ col, const float* __restrict__ bgl,
    const float* __restrict__ gl, const float* __restrict__ bl,
    unsigned short* __restrict__ xh)
{
    __shared__ int2 whs[4][4][64];   // [wave][head][edge] = {w_bits, src}
    int wv = threadIdx.x >> 6;
    int lane = threadIdx.x & 63;
    int node = blockIdx.x * 4 + wv;
    int s = offs[node], e = offs[node + 1];
    int deg = e - s;
    float4 ad = *(const float4*)(a_d + (size_t)node * 4);

    int c0 = 2 * lane, c1 = 2 * lane + 1;
    int head = lane >> 4;
    float acc0 = 0.f, acc1 = 0.f;
    float den = 1e-16f;

    if (deg <= 64) {
        int src = 0;
        float e0 = 0.f, e1 = 0.f, e2 = 0.f, e3 = 0.f;
        if (lane < deg) {
            src = col[s + lane];
            float4 as = *(const float4*)(a_s + (size_t)src * 4);
            float s0 = as.x + ad.x; s0 = fmaxf(s0, 0.2f * s0);
            float s1 = as.y + ad.y; s1 = fmaxf(s1, 0.2f * s1);
            float s2 = as.z + ad.z; s2 = fmaxf(s2, 0.2f * s2);
            float s3 = as.w + ad.w; s3 = fmaxf(s3, 0.2f * s3);
            e0 = __expf(s0); e1 = __expf(s1); e2 = __expf(s2); e3 = __expf(s3);
        }
        whs[wv][0][lane] = make_int2(__float_as_int(e0), src);
        whs[wv][1][lane] = make_int2(__float_as_int(e1), src);
        whs[wv][2][lane] = make_int2(__float_as_int(e2), src);
        whs[wv][3][lane] = make_int2(__float_as_int(e3), src);
        // same-wave LDS RAW: no barrier needed. 4-wide: 4 independent gathers in flight.
        const int2* wrow = &whs[wv][head][0];
        int dg4 = (deg + 3) & ~3;
        for (int j = 0; j < dg4; j += 4) {
            int2 q0 = wrow[j + 0], q1 = wrow[j + 1];
            int2 q2 = wrow[j + 2], q3 = wrow[j + 3];
            float w0 = __int_as_float(q0.x), w1 = __int_as_float(q1.x);
            float w2 = __int_as_float(q2.x), w3 = __int_as_float(q3.x);
            unsigned v0 = *(const unsigned*)(hb + (((unsigned)q0.y << 7) + (unsigned)c0));
            unsigned v1 = *(const unsigned*)(hb + (((unsigned)q1.y << 7) + (unsigned)c0));
            unsigned v2 = *(const unsigned*)(hb + (((unsigned)q2.y << 7) + (unsigned)c0));
            unsigned v3 = *(const unsigned*)(hb + (((unsigned)q3.y << 7) + (unsigned)c0));
            den += (w0 + w1) + (w2 + w3);
            acc0 = fmaf(w0, __uint_as_float(v0 << 16), acc0);
            acc1 = fmaf(w0, __uint_as_float(v0 & 0xffff0000u), acc1);
            acc0 = fmaf(w1, __uint_as_float(v1 << 16), acc0);
            acc1 = fmaf(w1, __uint_as_float(v1 & 0xffff0000u), acc1);
            acc0 = fmaf(w2, __uint_as_float(v2 << 16), acc0);
            acc1 = fmaf(w2, __uint_as_float(v2 & 0xffff0000u), acc1);
            acc0 = fmaf(w3, __uint_as_float(v3 << 16), acc0);
            acc1 = fmaf(w3, __uint_as_float(v3 & 0xffff0000u), acc1);
        }
    } else {
        for (int j = s; j < e; j++) {
            int src = col[j];
            float4 as = *(const float4*)(a_s + (size_t)src * 4);
            float sh = (head == 0) ? (as.x + ad.x) : (head == 1) ? (as.y + ad.y)
                     : (head == 2) ? (as.z + ad.z) : (as.w + ad.w);
            sh = fmaxf(sh, 0.2f * sh);
            float wj = __expf(sh);
            den += wj;
            unsigned hv = *(const unsigned*)(hb + (((unsigned)src << 7) + (unsigned)c0));
            acc0 = fmaf(wj, __uint_as_float(hv << 16), acc0);
            acc1 = fmaf(wj, __uint_as_float(hv & 0xffff0000u), acc1);
        }
    }
    float inv = 1.f / den;
    acc0 *= inv;
    acc1 *= inv;

    // epilogue: + bias, ReLU, residual (bf16 x), LayerNorm, write x
    float o0 = fmaxf(acc0 + bgl[c0], 0.f);
    float o1 = fmaxf(acc1 + bgl[c1], 0.f);
    size_t xi = (size_t)node * HID;
    unsigned ph = *(const unsigned*)(xh + xi + c0);
    float t0 = __uint_as_float(ph << 16) + o0;
    float t1 = __uint_as_float(ph & 0xffff0000u) + o1;
    float mu = wave_reduce_sum(t0 + t1) * (1.f / 128.f);
    float e0 = t0 - mu, e1 = t1 - mu;
    float var = wave_reduce_sum(e0 * e0 + e1 * e1) * (1.f / 128.f);
    float r = 1.f / sqrtf(var + 1e-5f);
    float r0 = e0 * r * gl[c0] + bl[c0];
    float r1 = e1 * r * gl[c1] + bl[c1];
    *(unsigned*)(xh + xi + c0) = (unsigned)bf16_rne(r0) | ((unsigned)bf16_rne(r1) << 16);
}

// ---------------- value head ----------------
__global__ void pool_sum(const unsigned short* __restrict__ xh, float* __restrict__ partial) {
    int t = threadIdx.x;
    int base = blockIdx.x * 256;
    float s = 0.f;
    for (int i = 0; i < 256; i++)
        s += bf2f(xh[(size_t)(base + i) * HID + t]);
    partial[blockIdx.x * 128 + t] = s;
}

__global__ void value_mlp(const float* __restrict__ partial,
                          const float* __restrict__ w1t, const float* __restrict__ b1,
                          const float* __restrict__ w2t, const float* __restrict__ b2,
                          const float* __restrict__ W3, const float* __restrict__ b3,
                          float* __restrict__ out)
{
    __shared__ float p[128], h1[128], h2[64];
    int t = threadIdx.x;   // 128
    float s = 0.f;
    for (int i = 0; i < 256; i++) s += partial[i * 128 + t];
    p[t] = s * (1.f / (float)NNODES);
    __syncthreads();
    float a = b1[t];
    const float4* wr = (const float4*)(w1t + (size_t)t * 128);
#pragma unroll
    for (int k4 = 0; k4 < 32; k4++) {
        float4 w = wr[k4];
        a += p[4 * k4] * w.x + p[4 * k4 + 1] * w.y + p[4 * k4 + 2] * w.z + p[4 * k4 + 3] * w.w;
    }
    h1[t] = fmaxf(a, 0.f);
    __syncthreads();
    if (t < 64) {
        float a2 = b2[t];
        const float4* wr2 = (const float4*)(w2t + (size_t)t * 128);
#pragma unroll
        for (int k4 = 0; k4 < 32; k4++) {
            float4 w = wr2[k4];
            a2 += h1[4 * k4] * w.x + h1[4 * k4 + 1] * w.y + h1[4 * k4 + 2] * w.z + h1[4 * k4 + 3] * w.w;
        }
        h2[t] = fmaxf(a2, 0.f);
    }
    __syncthreads();
    if (t == 0) {
        float v = b3[0];
        for (int k = 0; k < 64; k++) v = fmaf(h2[k], W3[k], v);
        out[NDATA * 2] = v;
    }
}

extern "C" void kernel_launch(void* const* d_in, const int* in_sizes, int n_in,
                              void* d_out, int out_size, void* d_ws, size_t ws_size,
                              hipStream_t stream)
{
    const float* feat  = (const float*)d_in[0];
    const int*   ei    = (const int*)d_in[1];
    const float* W_emb = (const float*)d_in[2];
    const float* b_emb = (const float*)d_in[3];
    const float* ln0g  = (const float*)d_in[4];
    const float* ln0b  = (const float*)d_in[5];
    const float* Wg    = (const float*)d_in[6];
    const float* att_s = (const float*)d_in[7];
    const float* att_d = (const float*)d_in[8];
    const float* bg    = (const float*)d_in[9];
    const float* lng   = (const float*)d_in[10];
    const float* lnb   = (const float*)d_in[11];
    const float* pW1 = (const float*)d_in[12]; const float* pb1 = (const float*)d_in[13];
    const float* pW2 = (const float*)d_in[14]; const float* pb2 = (const float*)d_in[15];
    const float* pW3 = (const float*)d_in[16]; const float* pb3 = (const float*)d_in[17];
    const float* vW1 = (const float*)d_in[18]; const float* vb1 = (const float*)d_in[19];
    const float* vW2 = (const float*)d_in[20]; const float* vb2 = (const float*)d_in[21];
    const float* vW3 = (const float*)d_in[22]; const float* vb3 = (const float*)d_in[23];
    float* out = (float*)d_out;
    int Eo = in_sizes[1] / 2;

    // workspace layout
    unsigned short* xh = (unsigned short*)d_ws;              // 65536*128 bf16
    unsigned short* hb = xh + (size_t)NNODES * HID;          // h bf16; reused as ph1h
    float* a_s = (float*)(hb + (size_t)NNODES * HID);
    float* a_d = a_s + NNODES * HEADS;
    unsigned short* wgt_h = (unsigned short*)(a_d + NNODES * HEADS);  // 4*144*128
    unsigned short* wgt_l = wgt_h + 4 * 144 * 128;
    unsigned short* pw1h  = wgt_l + 4 * 144 * 128;           // 128*128
    unsigned short* pw1l  = pw1h + 128 * 128;
    unsigned short* pw2h  = pw1l + 128 * 128;                // 64*128
    unsigned short* pw2l  = pw2h + 64 * 128;
    float* w1t  = (float*)(pw2l + 64 * 128);                 // 128*128 f32
    float* w2t  = w1t + 128 * 128;                           // 64*128 f32
    float* partial = w2t + 64 * 128;                         // 256*128 f32
    int* deg    = (int*)(partial + 256 * 128);
    int* offs   = deg + NNODES;
    int* cursor = offs + NNODES + 2;
    int* bsum   = cursor + NNODES;
    int* col    = bsum + 256;
    unsigned short* ph1h = hb;

    // merged embedding + weight prep (embed blocks first, then 480 prep blocks)
    prep_embed<<<NNODES / 4 + 480, 256, 0, stream>>>(
        feat, W_emb, b_emb, ln0g, ln0b, xh,
        Wg, att_s, att_d, pW1, pW2, vW1, vW2,
        wgt_h, wgt_l, pw1h, pw1l, pw2h, pw2l, w1t, w2t);

    // CSR build (dst -> src list), self-loops included (+1 folded into scan1)
    hipMemsetAsync(deg, 0, (size_t)NNODES * 4, stream);
    hist_kernel<<<(Eo + 255) / 256, 256, 0, stream>>>(ei, deg, Eo);
    scan1<<<256, 256, 0, stream>>>(deg, offs, bsum);
    scan3<<<256, 256, 0, stream>>>(offs, bsum, cursor, Eo);
    fill_kernel<<<(Eo + NNODES + 255) / 256, 256, 0, stream>>>(ei, cursor, col, Eo);

    // GAT layers
    for (int l = 0; l < LAYERS; l++) {
        mfma_gemm<9, 0><<<NNODES / 128, 512, 0, stream>>>(
            xh, wgt_h + (size_t)l * 144 * 128, wgt_l + (size_t)l * 144 * 128,
            nullptr, hb, a_s, a_d, nullptr, nullptr, nullptr);
        gat_agg<<<NNODES / 4, 256, 0, stream>>>(
            hb, a_s, a_d, offs, col, bg + l * HID, lng + l * HID, lnb + l * HID, xh);
    }

    // policy head: GEMM1 -> bf16-hi ph1; GEMM2 + fused [64,2] -> logits
    mfma_gemm<8, 1><<<NDATA / 128, 512, 0, stream>>>(
        xh, pw1h, pw1l, pb1, ph1h, nullptr, nullptr, nullptr, nullptr, nullptr);
    mfma_gemm<4, 2><<<NDATA / 128, 512, 0, stream>>>(
        ph1h, pw2h, pw2l, pb2, nullptr, nullptr, nullptr, pW3, pb3, out);

    // value head
    pool_sum<<<256, 128, 0, stream>>>(xh, partial);
    value_mlp<<<1, 128, 0, stream>>>(partial, w1t, vb1, w2t, vb2, vW3, vb3, out);
}

// Round 12
// 321.026 us; speedup vs baseline: 1.2729x; 1.0297x over previous
//
#include <hip/hip_runtime.h>

#define NNODES 65536
#define NDATA  32768
#define HID    128
#define HEADS  4
#define CHANS  32
#define LAYERS 4

using bf16x8 = __attribute__((ext_vector_type(8))) short;
using f32x4  = __attribute__((ext_vector_type(4))) float;

__device__ __forceinline__ float wave_reduce_sum(float v) {
#pragma unroll
    for (int m = 1; m < 64; m <<= 1) v += __shfl_xor(v, m, 64);
    return v;
}

__device__ __forceinline__ int wave_reduce_sum_i(int v) {
#pragma unroll
    for (int m = 1; m < 64; m <<= 1) v += __shfl_xor(v, m, 64);
    return v;
}

__device__ __forceinline__ unsigned short bf16_rne(float f) {
    unsigned u = __float_as_uint(f);
    return (unsigned short)((u + 0x7fffu + ((u >> 16) & 1u)) >> 16);
}
__device__ __forceinline__ float bf2f(unsigned short u) {
    return __uint_as_float((unsigned)u << 16);
}

__device__ __forceinline__ void gload_lds16(const unsigned short* g, unsigned short* l) {
    __builtin_amdgcn_global_load_lds(
        (const __attribute__((address_space(1))) void*)g,
        (__attribute__((address_space(3))) void*)l, 16, 0, 0);
}

// ---------------- CSR build ----------------
__global__ void hist_kernel(const int* __restrict__ ei, int* __restrict__ deg, int Eo) {
    int e = blockIdx.x * 256 + threadIdx.x;
    if (e >= Eo) return;
    atomicAdd(&deg[ei[Eo + e]], 1);   // dst row
}

// reads deg+1 (self-loop folded here; deg zeroed by memset)
__global__ void scan1(const int* __restrict__ deg, int* __restrict__ offs, int* __restrict__ bsum) {
    __shared__ int s[256];
    int t = threadIdx.x, b = blockIdx.x;
    int v = deg[b * 256 + t] + 1;
    s[t] = v;
    __syncthreads();
    for (int off = 1; off < 256; off <<= 1) {
        int add = (t >= off) ? s[t - off] : 0;
        __syncthreads();
        s[t] += add;
        __syncthreads();
    }
    offs[b * 256 + t] = s[t] - v;
    if (t == 255) bsum[b] = s[255];
}

// scan2 folded in: block b reduces bsum[0..b-1] itself (256 threads, masked)
__global__ void scan3(int* __restrict__ offs, const int* __restrict__ bsum,
                      int* __restrict__ cursor, int Eo) {
    __shared__ int ws[4];
    int b = blockIdx.x, t = threadIdx.x;
    int v = (t < b) ? bsum[t] : 0;
    v = wave_reduce_sum_i(v);
    if ((t & 63) == 0) ws[t >> 6] = v;
    __syncthreads();
    int base = ws[0] + ws[1] + ws[2] + ws[3];
    int i = b * 256 + t;
    int o = offs[i] + base;
    offs[i] = o;
    cursor[i] = o;
    if (i == 0) offs[NNODES] = Eo + NNODES;
}

__global__ void fill_kernel(const int* __restrict__ ei, int* __restrict__ cursor,
                            int* __restrict__ col, int Eo) {
    int e = blockIdx.x * 256 + threadIdx.x;
    int Etot = Eo + NNODES;
    if (e >= Etot) return;
    int src, dst;
    if (e < Eo) { src = ei[e]; dst = ei[Eo + e]; }
    else        { src = dst = e - Eo; }
    int pos = atomicAdd(&cursor[dst], 1);
    col[pos] = src;
}

// ------- merged: embedding (blocks 0..16383) + all weight prep (blocks 16384..) -------
__global__ __launch_bounds__(256) void prep_embed(
    const float* __restrict__ feat, const float* __restrict__ W_emb,
    const float* __restrict__ b_emb, const float* __restrict__ ln0g,
    const float* __restrict__ ln0b, unsigned short* __restrict__ xh,
    const float* __restrict__ Wg, const float* __restrict__ attS,
    const float* __restrict__ attD,
    const float* __restrict__ pW1, const float* __restrict__ pW2,
    const float* __restrict__ vW1, const float* __restrict__ vW2,
    unsigned short* __restrict__ wh, unsigned short* __restrict__ wl,
    unsigned short* __restrict__ w1h, unsigned short* __restrict__ w1l,
    unsigned short* __restrict__ w2h, unsigned short* __restrict__ w2l,
    float* __restrict__ w1t, float* __restrict__ w2t)
{
    if (blockIdx.x < NNODES / 4) {
        // ---- embedding + LN + ReLU -> xh (bf16) ----
        int node = blockIdx.x * 4 + (threadIdx.x >> 6);
        int lane = threadIdx.x & 63;
        float f[10];
#pragma unroll
        for (int i = 0; i < 10; i++) f[i] = feat[node * 10 + i];
        int c0 = 2 * lane, c1 = c0 + 1;
        float v0 = b_emb[c0], v1 = b_emb[c1];
#pragma unroll
        for (int i = 0; i < 10; i++) {
            v0 = fmaf(f[i], W_emb[i * HID + c0], v0);
            v1 = fmaf(f[i], W_emb[i * HID + c1], v1);
        }
        float mu = wave_reduce_sum(v0 + v1) * (1.f / 128.f);
        float e0 = v0 - mu, e1 = v1 - mu;
        float var = wave_reduce_sum(e0 * e0 + e1 * e1) * (1.f / 128.f);
        float r = 1.f / sqrtf(var + 1e-5f);
        float r0 = fmaxf(e0 * r * ln0g[c0] + ln0b[c0], 0.f);
        float r1 = fmaxf(e1 * r * ln0g[c1] + ln0b[c1], 0.f);
        *(unsigned*)(xh + (size_t)node * HID + c0) =
            (unsigned)bf16_rne(r0) | ((unsigned)bf16_rne(r1) << 16);
        return;
    }
    int id = (blockIdx.x - NNODES / 4) * 256 + threadIdx.x;
    if (id < 4 * 144 * 128) {
        int l = id / (144 * 128);
        int rem = id % (144 * 128);
        int n = rem / 128, k = rem % 128;
        const float* W = Wg + (size_t)l * HID * HID;
        float v = 0.f;
        if (n < 128) {
            v = W[k * HID + n];
        } else if (n < 136) {
            int h = (n - 128) & 3;
            const float* av = ((n - 128) < 4 ? attS : attD) + l * HID + h * CHANS;
            for (int c = 0; c < CHANS; c++) v += W[k * HID + h * CHANS + c] * av[c];
        }
        unsigned short hh = bf16_rne(v);
        int t = n >> 4, bcol = n & 15;
        int ks = k >> 5, kq = (k >> 3) & 3, e = k & 7;
        size_t o = (size_t)l * (144 * 128) + (size_t)(((t * 4 + ks) * 64) + (kq * 16 + bcol)) * 8 + e;
        wh[o] = hh;
        wl[o] = bf16_rne(v - bf2f(hh));
        return;
    }
    id -= 4 * 144 * 128;
    if (id < 24576) {
        int n, k;
        float v;
        unsigned short *dh, *dl;
        if (id < 16384) {
            n = id / 128; k = id % 128;
            v = pW1[k * 128 + n];
            dh = w1h; dl = w1l;
        } else {
            int j = id - 16384;
            n = j / 128; k = j % 128;
            v = pW2[k * 64 + n];
            dh = w2h; dl = w2l;
        }
        unsigned short hh = bf16_rne(v);
        int t = n >> 4, bcol = n & 15;
        int ks = k >> 5, kq = (k >> 3) & 3, e = k & 7;
        size_t o = (size_t)(((t * 4 + ks) * 64) + (kq * 16 + bcol)) * 8 + e;
        dh[o] = hh;
        dl[o] = bf16_rne(v - bf2f(hh));
        return;
    }
    id -= 24576;
    if (id < 16384) {
        int t = id >> 7, k = id & 127;
        w1t[t * 128 + k] = vW1[k * 128 + t];
    } else if (id < 24576) {
        int j = id - 16384;
        int t = j >> 7, k = j & 127;
        w2t[t * 128 + k] = vW2[k * 64 + t];
    }
}

// ---------------- MFMA GEMM, K=128, 2-product (Ah*Bh + Ah*Bl) ----
// A read as bf16-hi only; B keeps full hi/lo split.
// 512 thr = 8 waves; BM=128; B staged via global_load_lds in 2 K-phases.
// EPI 0: GAT (tiles 0..7 -> hb bf16; tile 8 cols 0..3 -> a_s, 4..7 -> a_d)
// EPI 1: bias+relu -> bf16 outH
// EPI 2: bias+relu + fused final layer [64]x[64,2] -> logits (shfl-reduce)
template <int NT, int EPI>
__global__ __launch_bounds__(512, 4) void mfma_gemm(
    const unsigned short* __restrict__ Ah,
    const unsigned short* __restrict__ Bh, const unsigned short* __restrict__ Bl,
    const float* __restrict__ bias,
    unsigned short* __restrict__ outH,
    float* __restrict__ a_s, float* __restrict__ a_d,
    const float* __restrict__ wfin, const float* __restrict__ bfin,
    float* __restrict__ outF)
{
    __shared__ unsigned short lds[NT * 2048];

    int tid = threadIdx.x;
    int wid = tid >> 6, l = tid & 63;
    int row = blockIdx.x * 128 + wid * 16 + (l & 15);
    int kg = (l >> 4) * 8;

    const unsigned short* arh = Ah + (size_t)row * 128 + kg;
    bf16x8 afh[4];
#pragma unroll
    for (int ks = 0; ks < 4; ks++) afh[ks] = *(const bf16x8*)(arh + ks * 32);

    f32x4 acc[NT];
#pragma unroll
    for (int t = 0; t < NT; t++) acc[t] = (f32x4){0.f, 0.f, 0.f, 0.f};

#pragma unroll
    for (int p = 0; p < 2; p++) {
        __syncthreads();   // all waves done reading previous LDS contents
        for (int c = wid; c < 4 * NT; c += 8) {
            int fr = c >> 1, lo = c & 1;
            int t = fr >> 1, ksl = fr & 1;
            const unsigned short* src = (lo ? Bl : Bh)
                + ((size_t)(t * 4 + p * 2 + ksl) << 9) + ((unsigned)l << 3);
            gload_lds16(src, &lds[(size_t)c << 9]);
        }
        __syncthreads();   // drains vmcnt (global_load_lds) before reads
#pragma unroll
        for (int ksl = 0; ksl < 2; ksl++) {
            int ks = p * 2 + ksl;
#pragma unroll
            for (int t = 0; t < NT; t++) {
                const unsigned short* bp = &lds[(((t * 2 + ksl) << 1) << 9) + (l << 3)];
                bf16x8 bh  = *(const bf16x8*)bp;
                bf16x8 blo = *(const bf16x8*)(bp + 512);
                acc[t] = __builtin_amdgcn_mfma_f32_16x16x32_bf16(afh[ks], bh,  acc[t], 0, 0, 0);
                acc[t] = __builtin_amdgcn_mfma_f32_16x16x32_bf16(afh[ks], blo, acc[t], 0, 0, 0);
            }
        }
    }

    // C/D layout: col = lane&15, row = (lane>>4)*4 + reg   [HW-verified]
    int ecol = l & 15;
    int er0 = blockIdx.x * 128 + wid * 16 + ((l >> 4) << 2);

    if constexpr (EPI == 0) {
#pragma unroll
        for (int t = 0; t < 8; t++)
#pragma unroll
            for (int j = 0; j < 4; j++)
                outH[(size_t)(er0 + j) * 128 + t * 16 + ecol] = bf16_rne(acc[t][j]);
#pragma unroll
        for (int j = 0; j < 4; j++) {
            float v = acc[8][j];
            if (ecol < 4)      a_s[(er0 + j) * 4 + ecol] = v;
            else if (ecol < 8) a_d[(er0 + j) * 4 + (ecol - 4)] = v;
        }
    } else if constexpr (EPI == 1) {
#pragma unroll
        for (int t = 0; t < NT; t++)
#pragma unroll
            for (int j = 0; j < 4; j++) {
                float v = fmaxf(acc[t][j] + bias[t * 16 + ecol], 0.f);
                outH[(size_t)(er0 + j) * 128 + t * 16 + ecol] = bf16_rne(v);
            }
    } else {
        float p0[4], p1[4];
#pragma unroll
        for (int j = 0; j < 4; j++) { p0[j] = 0.f; p1[j] = 0.f; }
#pragma unroll
        for (int t = 0; t < NT; t++) {
            int cc = t * 16 + ecol;
            float w0 = wfin[cc * 2 + 0], w1 = wfin[cc * 2 + 1];
#pragma unroll
            for (int j = 0; j < 4; j++) {
                float v = fmaxf(acc[t][j] + bias[cc], 0.f);
                p0[j] = fmaf(v, w0, p0[j]);
                p1[j] = fmaf(v, w1, p1[j]);
            }
        }
#pragma unroll
        for (int m = 1; m < 16; m <<= 1)
#pragma unroll
            for (int j = 0; j < 4; j++) {
                p0[j] += __shfl_xor(p0[j], m, 64);
                p1[j] += __shfl_xor(p1[j], m, 64);
            }
        if (ecol == 0) {
            float b0 = bfin[0], b1 = bfin[1];
#pragma unroll
            for (int j = 0; j < 4; j++) {
                outF[(er0 + j) * 2 + 0] = p0[j] + b0;
                outF[(er0 + j) * 2 + 1] = p1[j] + b1;
            }
        }
    }
}

// ------- fused: per-dst softmax (no-max, __expf) + 8-wide ILP aggregate + epilogue ----
__global__ __launch_bounds__(256, 4) void gat_agg(
    const unsigned short* __restrict__ hb, const float* __restrict__ a_s,
    const float* __restrict__ a_d, const int* __restrict__ offs,
    const int* __restrict__ col, const float* __restrict__ bgl,
    const float* __restrict__ gl, const float* __restrict__ bl,
    unsigned short* __restrict__ xh)
{
    __shared__ int2 whs[4][4][64];   // [wave][head][edge] = {w_bits, src}
    int wv = threadIdx.x >> 6;
    int lane = threadIdx.x & 63;
    int node = blockIdx.x * 4 + wv;
    int s = offs[node], e = offs[node + 1];
    int deg = e - s;
    float4 ad = *(const float4*)(a_d + (size_t)node * 4);

    int c0 = 2 * lane, c1 = 2 * lane + 1;
    int head = lane >> 4;
    float acc0 = 0.f, acc1 = 0.f;
    float den = 1e-16f;

    if (deg <= 64) {
        int src = 0;
        float e0 = 0.f, e1 = 0.f, e2 = 0.f, e3 = 0.f;
        if (lane < deg) {
            src = col[s + lane];
            float4 as = *(const float4*)(a_s + (size_t)src * 4);
            float s0 = as.x + ad.x; s0 = fmaxf(s0, 0.2f * s0);
            float s1 = as.y + ad.y; s1 = fmaxf(s1, 0.2f * s1);
            float s2 = as.z + ad.z; s2 = fmaxf(s2, 0.2f * s2);
            float s3 = as.w + ad.w; s3 = fmaxf(s3, 0.2f * s3);
            e0 = __expf(s0); e1 = __expf(s1); e2 = __expf(s2); e3 = __expf(s3);
        }
        whs[wv][0][lane] = make_int2(__float_as_int(e0), src);
        whs[wv][1][lane] = make_int2(__float_as_int(e1), src);
        whs[wv][2][lane] = make_int2(__float_as_int(e2), src);
        whs[wv][3][lane] = make_int2(__float_as_int(e3), src);
        // same-wave LDS RAW: no barrier needed. 8-wide batch: 8 independent gathers
        // in flight per wave -> 1-2 latency exposures per node (Poisson(9) degree).
        const int2* wrow = &whs[wv][head][0];
        int dg8 = (deg + 7) & ~7;
        for (int j = 0; j < dg8; j += 8) {
            int2 q[8];
#pragma unroll
            for (int u = 0; u < 8; u++) q[u] = wrow[j + u];
            unsigned hv[8];
#pragma unroll
            for (int u = 0; u < 8; u++)
                hv[u] = *(const unsigned*)(hb + (((unsigned)q[u].y << 7) + (unsigned)c0));
#pragma unroll
            for (int u = 0; u < 8; u++) {
                float w = __int_as_float(q[u].x);
                den += w;
                acc0 = fmaf(w, __uint_as_float(hv[u] << 16), acc0);
                acc1 = fmaf(w, __uint_as_float(hv[u] & 0xffff0000u), acc1);
            }
        }
    } else {
        for (int j = s; j < e; j++) {
            int src = col[j];
            float4 as = *(const float4*)(a_s + (size_t)src * 4);
            float sh = (head == 0) ? (as.x + ad.x) : (head == 1) ? (as.y + ad.y)
                     : (head == 2) ? (as.z + ad.z) : (as.w + ad.w);
            sh = fmaxf(sh, 0.2f * sh);
            float wj = __expf(sh);
            den += wj;
            unsigned hv = *(const unsigned*)(hb + (((unsigned)src << 7) + (unsigned)c0));
            acc0 = fmaf(wj, __uint_as_float(hv << 16), acc0);
            acc1 = fmaf(wj, __uint_as_float(hv & 0xffff0000u), acc1);
        }
    }
    float inv = 1.f / den;
    acc0 *= inv;
    acc1 *= inv;

    // epilogue: + bias, ReLU, residual (bf16 x), LayerNorm, write x
    float o0 = fmaxf(acc0 + bgl[c0], 0.f);
    float o1 = fmaxf(acc1 + bgl[c1], 0.f);
    size_t xi = (size_t)node * HID;
    unsigned ph = *(const unsigned*)(xh + xi + c0);
    float t0 = __uint_as_float(ph << 16) + o0;
    float t1 = __uint_as_float(ph & 0xffff0000u) + o1;
    float mu = wave_reduce_sum(t0 + t1) * (1.f / 128.f);
    float e0 = t0 - mu, e1 = t1 - mu;
    float var = wave_reduce_sum(e0 * e0 + e1 * e1) * (1.f / 128.f);
    float r = 1.f / sqrtf(var + 1e-5f);
    float r0 = e0 * r * gl[c0] + bl[c0];
    float r1 = e1 * r * gl[c1] + bl[c1];
    *(unsigned*)(xh + xi + c0) = (unsigned)bf16_rne(r0) | ((unsigned)bf16_rne(r1) << 16);
}

// ---------------- value head ----------------
__global__ void pool_sum(const unsigned short* __restrict__ xh, float* __restrict__ partial) {
    int t = threadIdx.x;
    int base = blockIdx.x * 256;
    float s = 0.f;
    for (int i = 0; i < 256; i++)
        s += bf2f(xh[(size_t)(base + i) * HID + t]);
    partial[blockIdx.x * 128 + t] = s;
}

__global__ void value_mlp(const float* __restrict__ partial,
                          const float* __restrict__ w1t, const float* __restrict__ b1,
                          const float* __restrict__ w2t, const float* __restrict__ b2,
                          const float* __restrict__ W3, const float* __restrict__ b3,
                          float* __restrict__ out)
{
    __shared__ float p[128], h1[128], h2[64];
    int t = threadIdx.x;   // 128
    float s = 0.f;
    for (int i = 0; i < 256; i++) s += partial[i * 128 + t];
    p[t] = s * (1.f / (float)NNODES);
    __syncthreads();
    float a = b1[t];
    const float4* wr = (const float4*)(w1t + (size_t)t * 128);
#pragma unroll
    for (int k4 = 0; k4 < 32; k4++) {
        float4 w = wr[k4];
        a += p[4 * k4] * w.x + p[4 * k4 + 1] * w.y + p[4 * k4 + 2] * w.z + p[4 * k4 + 3] * w.w;
    }
    h1[t] = fmaxf(a, 0.f);
    __syncthreads();
    if (t < 64) {
        float a2 = b2[t];
        const float4* wr2 = (const float4*)(w2t + (size_t)t * 128);
#pragma unroll
        for (int k4 = 0; k4 < 32; k4++) {
            float4 w = wr2[k4];
            a2 += h1[4 * k4] * w.x + h1[4 * k4 + 1] * w.y + h1[4 * k4 + 2] * w.z + h1[4 * k4 + 3] * w.w;
        }
        h2[t] = fmaxf(a2, 0.f);
    }
    __syncthreads();
    if (t == 0) {
        float v = b3[0];
        for (int k = 0; k < 64; k++) v = fmaf(h2[k], W3[k], v);
        out[NDATA * 2] = v;
    }
}

extern "C" void kernel_launch(void* const* d_in, const int* in_sizes, int n_in,
                              void* d_out, int out_size, void* d_ws, size_t ws_size,
                              hipStream_t stream)
{
    const float* feat  = (const float*)d_in[0];
    const int*   ei    = (const int*)d_in[1];
    const float* W_emb = (const float*)d_in[2];
    const float* b_emb = (const float*)d_in[3];
    const float* ln0g  = (const float*)d_in[4];
    const float* ln0b  = (const float*)d_in[5];
    const float* Wg    = (const float*)d_in[6];
    const float* att_s = (const float*)d_in[7];
    const float* att_d = (const float*)d_in[8];
    const float* bg    = (const float*)d_in[9];
    const float* lng   = (const float*)d_in[10];
    const float* lnb   = (const float*)d_in[11];
    const float* pW1 = (const float*)d_in[12]; const float* pb1 = (const float*)d_in[13];
    const float* pW2 = (const float*)d_in[14]; const float* pb2 = (const float*)d_in[15];
    const float* pW3 = (const float*)d_in[16]; const float* pb3 = (const float*)d_in[17];
    const float* vW1 = (const float*)d_in[18]; const float* vb1 = (const float*)d_in[19];
    const float* vW2 = (const float*)d_in[20]; const float* vb2 = (const float*)d_in[21];
    const float* vW3 = (const float*)d_in[22]; const float* vb3 = (const float*)d_in[23];
    float* out = (float*)d_out;
    int Eo = in_sizes[1] / 2;

    // workspace layout
    unsigned short* xh = (unsigned short*)d_ws;              // 65536*128 bf16
    unsigned short* hb = xh + (size_t)NNODES * HID;          // h bf16; reused as ph1h
    float* a_s = (float*)(hb + (size_t)NNODES * HID);
    float* a_d = a_s + NNODES * HEADS;
    unsigned short* wgt_h = (unsigned short*)(a_d + NNODES * HEADS);  // 4*144*128
    unsigned short* wgt_l = wgt_h + 4 * 144 * 128;
    unsigned short* pw1h  = wgt_l + 4 * 144 * 128;           // 128*128
    unsigned short* pw1l  = pw1h + 128 * 128;
    unsigned short* pw2h  = pw1l + 128 * 128;                // 64*128
    unsigned short* pw2l  = pw2h + 64 * 128;
    float* w1t  = (float*)(pw2l + 64 * 128);                 // 128*128 f32
    float* w2t  = w1t + 128 * 128;                           // 64*128 f32
    float* partial = w2t + 64 * 128;                         // 256*128 f32
    int* deg    = (int*)(partial + 256 * 128);
    int* offs   = deg + NNODES;
    int* cursor = offs + NNODES + 2;
    int* bsum   = cursor + NNODES;
    int* col    = bsum + 256;
    unsigned short* ph1h = hb;

    // merged embedding + weight prep (embed blocks first, then 480 prep blocks)
    prep_embed<<<NNODES / 4 + 480, 256, 0, stream>>>(
        feat, W_emb, b_emb, ln0g, ln0b, xh,
        Wg, att_s, att_d, pW1, pW2, vW1, vW2,
        wgt_h, wgt_l, pw1h, pw1l, pw2h, pw2l, w1t, w2t);

    // CSR build (dst -> src list), self-loops included (+1 folded into scan1)
    hipMemsetAsync(deg, 0, (size_t)NNODES * 4, stream);
    hist_kernel<<<(Eo + 255) / 256, 256, 0, stream>>>(ei, deg, Eo);
    scan1<<<256, 256, 0, stream>>>(deg, offs, bsum);
    scan3<<<256, 256, 0, stream>>>(offs, bsum, cursor, Eo);
    fill_kernel<<<(Eo + NNODES + 255) / 256, 256, 0, stream>>>(ei, cursor, col, Eo);

    // GAT layers
    for (int l = 0; l < LAYERS; l++) {
        mfma_gemm<9, 0><<<NNODES / 128, 512, 0, stream>>>(
            xh, wgt_h + (size_t)l * 144 * 128, wgt_l + (size_t)l * 144 * 128,
            nullptr, hb, a_s, a_d, nullptr, nullptr, nullptr);
        gat_agg<<<NNODES / 4, 256, 0, stream>>>(
            hb, a_s, a_d, offs, col, bg + l * HID, lng + l * HID, lnb + l * HID, xh);
    }

    // policy head: GEMM1 -> bf16-hi ph1; GEMM2 + fused [64,2] -> logits
    mfma_gemm<8, 1><<<NDATA / 128, 512, 0, stream>>>(
        xh, pw1h, pw1l, pb1, ph1h, nullptr, nullptr, nullptr, nullptr, nullptr);
    mfma_gemm<4, 2><<<NDATA / 128, 512, 0, stream>>>(
        ph1h, pw2h, pw2l, pb2, nullptr, nullptr, nullptr, pW3, pb3, out);

    // value head
    pool_sum<<<256, 128, 0, stream>>>(xh, partial);
    value_mlp<<<1, 128, 0, stream>>>(partial, w1t, vb1, w2t, vb2, vW3, vb3, out);
}